// Round 1
// baseline (1243.679 us; speedup 1.0000x reference)
//
#include <hip/hip_runtime.h>
#include <hip/hip_bf16.h>

#define B_ 4
#define T_ 2048
#define C_ 1024
#define NH_ 16
#define FF_ 4096
#define NT_ (B_*T_)   // 8192 token rows

typedef short bf16x8 __attribute__((ext_vector_type(8)));
typedef float f32x4 __attribute__((ext_vector_type(4)));

#define LDS_AS(p) ((__attribute__((address_space(3))) uint32_t*)(p))
#define GLB_AS(p) ((const __attribute__((address_space(1))) uint32_t*)(p))

__device__ __forceinline__ float bf2f(__hip_bfloat16 v){ return __bfloat162float(v); }
__device__ __forceinline__ __hip_bfloat16 f2bf(float f){ return __float2bfloat16(f); }

__device__ __forceinline__ f32x4 mfma16(bf16x8 a, bf16x8 b, f32x4 c){
  return __builtin_amdgcn_mfma_f32_16x16x32_bf16(a, b, c, 0, 0, 0);
}

// ---------------- weight transpose + fp32->bf16 cast:  in[K][N] -> out[N][K] ----------------
__global__ __launch_bounds__(256) void transpose_bf16(const float* __restrict__ in,
                                                      __hip_bfloat16* __restrict__ out,
                                                      int K, int N) {
  __shared__ float tile[32][33];
  const int n0 = blockIdx.x * 32, k0 = blockIdx.y * 32;
  const int x = threadIdx.x & 31, y = threadIdx.x >> 5;   // y in 0..7
  #pragma unroll
  for (int i = 0; i < 4; i++)
    tile[y + 8*i][x] = in[(size_t)(k0 + y + 8*i) * N + n0 + x];
  __syncthreads();
  #pragma unroll
  for (int i = 0; i < 4; i++)
    out[(size_t)(n0 + y + 8*i) * K + k0 + x] = f2bf(tile[x][y + 8*i]);
}

// ---------------- LayerNorm fp32 -> bf16 (row = 1024) ----------------
__global__ __launch_bounds__(256) void ln_bf16(const float* __restrict__ x,
                                               const float* __restrict__ g,
                                               const float* __restrict__ b,
                                               __hip_bfloat16* __restrict__ out) {
  const int row = blockIdx.x;
  const int tid = threadIdx.x;
  float4 v = ((const float4*)(x + (size_t)row * C_))[tid];
  float s  = v.x + v.y + v.z + v.w;
  float s2 = v.x*v.x + v.y*v.y + v.z*v.z + v.w*v.w;
  #pragma unroll
  for (int off = 32; off > 0; off >>= 1) {
    s  += __shfl_down(s,  off, 64);
    s2 += __shfl_down(s2, off, 64);
  }
  __shared__ float red[8];
  const int w = tid >> 6, l = tid & 63;
  if (l == 0) { red[w] = s; red[4 + w] = s2; }
  __syncthreads();
  s  = red[0] + red[1] + red[2] + red[3];
  s2 = red[4] + red[5] + red[6] + red[7];
  const float mu   = s * (1.0f / C_);
  const float var  = s2 * (1.0f / C_) - mu * mu;
  const float rstd = rsqrtf(var + 1e-5f);
  float4 gv = ((const float4*)g)[tid];
  float4 bv = ((const float4*)b)[tid];
  ushort4 o;
  __hip_bfloat16 t;
  t = f2bf((v.x - mu) * rstd * gv.x + bv.x); o.x = *(unsigned short*)&t;
  t = f2bf((v.y - mu) * rstd * gv.y + bv.y); o.y = *(unsigned short*)&t;
  t = f2bf((v.z - mu) * rstd * gv.z + bv.z); o.z = *(unsigned short*)&t;
  t = f2bf((v.w - mu) * rstd * gv.w + bv.w); o.w = *(unsigned short*)&t;
  ((ushort4*)out)[(size_t)row * (C_/4) + tid] = o;
}

// ---------------- shared MFMA GEMM:  C[M][N] = A[M][K] * BT[N][K]^T  + epilogue ----------------
// MODE 0: out bf16 = C + bias            (QKV)
// MODE 1: out f32  = resid + C + bias    (proj)
// MODE 2: out bf16 = gelu(C + bias)      (FC)
// MODE 3: out f32  = resid + C + bias    (FC2)
template <int MODE>
__global__ __launch_bounds__(256) void gemm_bt(const __hip_bfloat16* __restrict__ A,
                                               const __hip_bfloat16* __restrict__ BT,
                                               const float* __restrict__ bias,
                                               const float* __restrict__ resid,
                                               void* __restrict__ outp,
                                               int N, int K) {
  __shared__ __hip_bfloat16 Als[128 * 32];
  __shared__ __hip_bfloat16 Bls[128 * 32];
  const int tid = threadIdx.x;
  const int w = tid >> 6, l = tid & 63;
  const int tile_n = blockIdx.x * 128;
  const int tile_m = blockIdx.y * 128;
  const int wm = (w >> 1) * 64, wn = (w & 1) * 64;

  f32x4 acc[4][4] = {};

  // staging: each wave covers 16 rows per global_load_lds, 2 instrs per operand
  const int srow = w * 16 + (l >> 2);
  const int scol = (l & 3) * 8;
  const __hip_bfloat16* Ag = A  + (size_t)(tile_m + srow) * K + scol;
  const __hip_bfloat16* Bg = BT + (size_t)(tile_n + srow) * K + scol;
  __hip_bfloat16* AlsW = &Als[(w * 16) * 32];
  __hip_bfloat16* BlsW = &Bls[(w * 16) * 32];

  const int m_ = (l & 15);
  const int kq = (l >> 4) * 8;

  for (int k0 = 0; k0 < K; k0 += 32) {
    __builtin_amdgcn_global_load_lds(GLB_AS(Ag + k0),                 LDS_AS(AlsW),           16, 0, 0);
    __builtin_amdgcn_global_load_lds(GLB_AS(Ag + (size_t)64*K + k0),  LDS_AS(AlsW + 64*32),   16, 0, 0);
    __builtin_amdgcn_global_load_lds(GLB_AS(Bg + k0),                 LDS_AS(BlsW),           16, 0, 0);
    __builtin_amdgcn_global_load_lds(GLB_AS(Bg + (size_t)64*K + k0),  LDS_AS(BlsW + 64*32),   16, 0, 0);
    __syncthreads();
    bf16x8 af[4], bfr[4];
    #pragma unroll
    for (int mi = 0; mi < 4; mi++) af[mi]  = *(const bf16x8*)&Als[(wm + mi*16 + m_) * 32 + kq];
    #pragma unroll
    for (int ni = 0; ni < 4; ni++) bfr[ni] = *(const bf16x8*)&Bls[(wn + ni*16 + m_) * 32 + kq];
    #pragma unroll
    for (int mi = 0; mi < 4; mi++)
      #pragma unroll
      for (int ni = 0; ni < 4; ni++)
        acc[mi][ni] = mfma16(af[mi], bfr[ni], acc[mi][ni]);
    __syncthreads();
  }

  // epilogue: C/D layout col=lane&15, row=(lane>>4)*4+reg
  const int r0 = tile_m + wm + (l >> 4) * 4;
  const int c0 = tile_n + wn + m_;
  #pragma unroll
  for (int mi = 0; mi < 4; mi++) {
    #pragma unroll
    for (int r = 0; r < 4; r++) {
      const int row = r0 + mi * 16 + r;
      #pragma unroll
      for (int ni = 0; ni < 4; ni++) {
        const int col = c0 + ni * 16;
        float v = acc[mi][ni][r] + bias[col];
        if (MODE == 0) {
          ((__hip_bfloat16*)outp)[(size_t)row * N + col] = f2bf(v);
        } else if (MODE == 1 || MODE == 3) {
          ((float*)outp)[(size_t)row * N + col] = resid[(size_t)row * N + col] + v;
        } else { // gelu, overflow-safe tanh via exp
          const float u = 0.7978845608028654f * (v + 0.044715f * v * v * v);
          const float e = __expf(2.0f * u);
          const float th = 1.0f - 2.0f / (e + 1.0f);
          ((__hip_bfloat16*)outp)[(size_t)row * N + col] = f2bf(0.5f * v * (1.0f + th));
        }
      }
    }
  }
}

// ---------------- flash attention (causal), one block per (b, head, 64-row Q tile) ----------------
__global__ __launch_bounds__(256) void flash_attn(const __hip_bfloat16* __restrict__ qkv,
                                                  __hip_bfloat16* __restrict__ y) {
  const int qt = blockIdx.x;            // 0..31
  const int bh = blockIdx.y;            // 0..63
  const int b  = bh >> 4, h = bh & 15;
  const int tid = threadIdx.x, w = tid >> 6, l = tid & 63;
  const int q0 = qt * 64;

  __shared__ __hip_bfloat16 Qls[64 * 72];
  __shared__ __hip_bfloat16 Kls[64 * 72];
  __shared__ __hip_bfloat16 VT[64 * 72];
  __shared__ __hip_bfloat16 Pls[64 * 72];
  __shared__ float Sls[64 * 65];
  __shared__ float mls[64], lls[64], als[64];

  const size_t baseq = ((size_t)b * T_ + q0) * (3 * C_) + h * 64;

  // stage Q (pre-scaled by 1/sqrt(64) = 0.125, exact in bf16)
  for (int i = tid; i < 512; i += 256) {
    const int r = i >> 3, c8 = (i & 7) * 8;
    uint4 qq = *(const uint4*)&qkv[baseq + (size_t)r * (3*C_) + c8];
    const __hip_bfloat16* qp = (const __hip_bfloat16*)&qq;
    #pragma unroll
    for (int j = 0; j < 8; j++) Qls[r * 72 + c8 + j] = f2bf(bf2f(qp[j]) * 0.125f);
  }
  if (tid < 64) { mls[tid] = -1e30f; lls[tid] = 0.0f; }
  f32x4 accO[4] = {};
  __syncthreads();

  const int m_ = (l & 15);
  const int q_ = (l >> 4);

  for (int kt = 0; kt <= qt; kt++) {
    const size_t basek = ((size_t)b * T_ + kt * 64) * (3 * C_) + C_ + h * 64;
    const size_t basev = basek + C_;
    for (int i = tid; i < 512; i += 256) {
      const int r = i >> 3, c8 = (i & 7) * 8;
      *(uint4*)&Kls[r * 72 + c8] = *(const uint4*)&qkv[basek + (size_t)r * (3*C_) + c8];
      uint4 vv = *(const uint4*)&qkv[basev + (size_t)r * (3*C_) + c8];
      const __hip_bfloat16* vp = (const __hip_bfloat16*)&vv;
      #pragma unroll
      for (int j = 0; j < 8; j++) VT[(c8 + j) * 72 + r] = vp[j];
    }
    __syncthreads();

    // S = Q K^T, wave w owns rows [16w, 16w+16)
    bf16x8 aq0 = *(const bf16x8*)&Qls[(w*16 + m_) * 72 + q_*8];
    bf16x8 aq1 = *(const bf16x8*)&Qls[(w*16 + m_) * 72 + 32 + q_*8];
    #pragma unroll
    for (int ni = 0; ni < 4; ni++) {
      f32x4 s = {};
      bf16x8 bk0 = *(const bf16x8*)&Kls[(ni*16 + m_) * 72 + q_*8];
      bf16x8 bk1 = *(const bf16x8*)&Kls[(ni*16 + m_) * 72 + 32 + q_*8];
      s = mfma16(aq0, bk0, s);
      s = mfma16(aq1, bk1, s);
      #pragma unroll
      for (int r = 0; r < 4; r++)
        Sls[(w*16 + q_*4 + r) * 65 + ni*16 + m_] = s[r];
    }
    __syncthreads();

    // online softmax: thread r (< 64) owns row r
    if (tid < 64) {
      const int r = tid;
      const int nv = (kt == qt) ? (r + 1) : 64;   // causal validity
      float mx = -1e30f;
      for (int c = 0; c < nv; c++) mx = fmaxf(mx, Sls[r * 65 + c]);
      const float mo = mls[r];
      const float mn = fmaxf(mo, mx);
      const float alpha = __expf(mo - mn);
      float sum = 0.0f;
      for (int c = 0; c < nv; c++) {
        const float p = __expf(Sls[r * 65 + c] - mn);
        sum += p;
        Pls[r * 72 + c] = f2bf(p);
      }
      for (int c = nv; c < 64; c++) Pls[r * 72 + c] = f2bf(0.0f);
      lls[r] = lls[r] * alpha + sum;
      mls[r] = mn;
      als[r] = alpha;
    }
    __syncthreads();

    // O = O*alpha + P V
    float av[4];
    #pragma unroll
    for (int r = 0; r < 4; r++) av[r] = als[w*16 + q_*4 + r];
    #pragma unroll
    for (int ni = 0; ni < 4; ni++)
      #pragma unroll
      for (int r = 0; r < 4; r++) accO[ni][r] *= av[r];
    bf16x8 ap0 = *(const bf16x8*)&Pls[(w*16 + m_) * 72 + q_*8];
    bf16x8 ap1 = *(const bf16x8*)&Pls[(w*16 + m_) * 72 + 32 + q_*8];
    #pragma unroll
    for (int ni = 0; ni < 4; ni++) {
      bf16x8 bv0 = *(const bf16x8*)&VT[(ni*16 + m_) * 72 + q_*8];
      bf16x8 bv1 = *(const bf16x8*)&VT[(ni*16 + m_) * 72 + 32 + q_*8];
      accO[ni] = mfma16(ap0, bv0, accO[ni]);
      accO[ni] = mfma16(ap1, bv1, accO[ni]);
    }
    __syncthreads();
  }

  // epilogue: y[b, q0+row, h*64 + col] = O / l
  const size_t ybase = ((size_t)b * T_ + q0) * C_ + h * 64;
  #pragma unroll
  for (int r = 0; r < 4; r++) {
    const int row = w*16 + q_*4 + r;
    const float linv = 1.0f / lls[row];
    #pragma unroll
    for (int ni = 0; ni < 4; ni++)
      y[ybase + (size_t)row * C_ + ni*16 + m_] = f2bf(accO[ni][r] * linv);
  }
}

// ---------------- launch ----------------
extern "C" void kernel_launch(void* const* d_in, const int* in_sizes, int n_in,
                              void* d_out, int out_size, void* d_ws, size_t ws_size,
                              hipStream_t stream) {
  const float* x      = (const float*)d_in[0];
  const float* ln1_g  = (const float*)d_in[1];
  const float* ln1_b  = (const float*)d_in[2];
  const float* w_attn = (const float*)d_in[3];
  const float* b_attn = (const float*)d_in[4];
  const float* w_proj = (const float*)d_in[5];
  const float* b_proj = (const float*)d_in[6];
  const float* ln2_g  = (const float*)d_in[7];
  const float* ln2_b  = (const float*)d_in[8];
  const float* w_fc   = (const float*)d_in[9];
  const float* b_fc   = (const float*)d_in[10];
  const float* w_fc2  = (const float*)d_in[11];
  const float* b_fc2  = (const float*)d_in[12];
  float* out = (float*)d_out;

  char* ws = (char*)d_ws;
  const size_t MB = 1024 * 1024;
  __hip_bfloat16* h      = (__hip_bfloat16*)(ws);                 // 16MB [0,16)
  __hip_bfloat16* qkv    = (__hip_bfloat16*)(ws + 16*MB);         // 48MB [16,64)
  __hip_bfloat16* y      = (__hip_bfloat16*)(ws + 64*MB);         // 16MB [64,80)
  float*          x2     = (float*)        (ws + 80*MB);          // 32MB [80,112)
  __hip_bfloat16* h2     = (__hip_bfloat16*)(ws + 64*MB);         // reuse y slot
  __hip_bfloat16* gbuf   = (__hip_bfloat16*)(ws);                 // 64MB reuse [0,64)
  __hip_bfloat16* wattnT = (__hip_bfloat16*)(ws + 112*MB);        // 6MB
  __hip_bfloat16* wprojT = (__hip_bfloat16*)(ws + 118*MB);        // 2MB
  __hip_bfloat16* wfcT   = (__hip_bfloat16*)(ws + 120*MB);        // 8MB
  __hip_bfloat16* wfc2T  = (__hip_bfloat16*)(ws + 128*MB);        // 8MB

  // weights: [K][N] fp32 -> [N][K] bf16
  transpose_bf16<<<dim3(3*C_/32, C_/32), 256, 0, stream>>>(w_attn, wattnT, C_, 3*C_);
  transpose_bf16<<<dim3(C_/32,  C_/32), 256, 0, stream>>>(w_proj, wprojT, C_, C_);
  transpose_bf16<<<dim3(FF_/32, C_/32), 256, 0, stream>>>(w_fc,   wfcT,   C_, FF_);
  transpose_bf16<<<dim3(C_/32, FF_/32), 256, 0, stream>>>(w_fc2,  wfc2T,  FF_, C_);

  // LN1
  ln_bf16<<<NT_, 256, 0, stream>>>(x, ln1_g, ln1_b, h);
  // QKV
  gemm_bt<0><<<dim3(3*C_/128, NT_/128), 256, 0, stream>>>(h, wattnT, b_attn, nullptr, qkv, 3*C_, C_);
  // attention
  flash_attn<<<dim3(T_/64, B_*NH_), 256, 0, stream>>>(qkv, y);
  // proj + residual -> x2 (fp32)
  gemm_bt<1><<<dim3(C_/128, NT_/128), 256, 0, stream>>>(y, wprojT, b_proj, x, x2, C_, C_);
  // LN2
  ln_bf16<<<NT_, 256, 0, stream>>>(x2, ln2_g, ln2_b, h2);
  // FC + gelu
  gemm_bt<2><<<dim3(FF_/128, NT_/128), 256, 0, stream>>>(h2, wfcT, b_fc, nullptr, gbuf, FF_, C_);
  // FC2 + residual -> out (fp32)
  gemm_bt<3><<<dim3(C_/128, NT_/128), 256, 0, stream>>>(gbuf, wfc2T, b_fc2, x2, out, C_, FF_);
}

// Round 2
// 760.778 us; speedup vs baseline: 1.6347x; 1.6347x over previous
//
#include <hip/hip_runtime.h>
#include <hip/hip_bf16.h>

#define B_ 4
#define T_ 2048
#define C_ 1024
#define NH_ 16
#define FF_ 4096
#define NT_ (B_*T_)   // 8192 token rows

typedef short bf16x8 __attribute__((ext_vector_type(8)));
typedef float f32x4 __attribute__((ext_vector_type(4)));

#define LDS_AS(p) ((__attribute__((address_space(3))) uint32_t*)(p))
#define GLB_AS(p) ((const __attribute__((address_space(1))) uint32_t*)(p))

__device__ __forceinline__ float bf2f(__hip_bfloat16 v){ return __bfloat162float(v); }
__device__ __forceinline__ __hip_bfloat16 f2bf(float f){ return __float2bfloat16(f); }

__device__ __forceinline__ f32x4 mfma16(bf16x8 a, bf16x8 b, f32x4 c){
  return __builtin_amdgcn_mfma_f32_16x16x32_bf16(a, b, c, 0, 0, 0);
}

// ---------------- weight transpose + fp32->bf16 cast:  in[K][N] -> out[N][K] ----------------
__global__ __launch_bounds__(256) void transpose_bf16(const float* __restrict__ in,
                                                      __hip_bfloat16* __restrict__ out,
                                                      int K, int N) {
  __shared__ float tile[32][33];
  const int n0 = blockIdx.x * 32, k0 = blockIdx.y * 32;
  const int x = threadIdx.x & 31, y = threadIdx.x >> 5;   // y in 0..7
  #pragma unroll
  for (int i = 0; i < 4; i++)
    tile[y + 8*i][x] = in[(size_t)(k0 + y + 8*i) * N + n0 + x];
  __syncthreads();
  #pragma unroll
  for (int i = 0; i < 4; i++)
    out[(size_t)(n0 + y + 8*i) * K + k0 + x] = f2bf(tile[x][y + 8*i]);
}

// ---------------- LayerNorm fp32 -> bf16 (row = 1024) ----------------
__global__ __launch_bounds__(256) void ln_bf16(const float* __restrict__ x,
                                               const float* __restrict__ g,
                                               const float* __restrict__ b,
                                               __hip_bfloat16* __restrict__ out) {
  const int row = blockIdx.x;
  const int tid = threadIdx.x;
  float4 v = ((const float4*)(x + (size_t)row * C_))[tid];
  float s  = v.x + v.y + v.z + v.w;
  float s2 = v.x*v.x + v.y*v.y + v.z*v.z + v.w*v.w;
  #pragma unroll
  for (int off = 32; off > 0; off >>= 1) {
    s  += __shfl_down(s,  off, 64);
    s2 += __shfl_down(s2, off, 64);
  }
  __shared__ float red[8];
  const int w = tid >> 6, l = tid & 63;
  if (l == 0) { red[w] = s; red[4 + w] = s2; }
  __syncthreads();
  s  = red[0] + red[1] + red[2] + red[3];
  s2 = red[4] + red[5] + red[6] + red[7];
  const float mu   = s * (1.0f / C_);
  const float var  = s2 * (1.0f / C_) - mu * mu;
  const float rstd = rsqrtf(var + 1e-5f);
  float4 gv = ((const float4*)g)[tid];
  float4 bv = ((const float4*)b)[tid];
  ushort4 o;
  __hip_bfloat16 t;
  t = f2bf((v.x - mu) * rstd * gv.x + bv.x); o.x = *(unsigned short*)&t;
  t = f2bf((v.y - mu) * rstd * gv.y + bv.y); o.y = *(unsigned short*)&t;
  t = f2bf((v.z - mu) * rstd * gv.z + bv.z); o.z = *(unsigned short*)&t;
  t = f2bf((v.w - mu) * rstd * gv.w + bv.w); o.w = *(unsigned short*)&t;
  ((ushort4*)out)[(size_t)row * (C_/4) + tid] = o;
}

// ---------------- shared MFMA GEMM:  C[M][N] = A[M][K] * BT[N][K]^T  + epilogue ----------------
// MODE 0: QKV. cols <2048 -> bf16 qk[row][col] (ld 2048); cols >=2048 -> bf16 vT[b,dg,t]
// MODE 1: out f32  = resid + C + bias    (proj)
// MODE 2: out bf16 = gelu(C + bias)      (FC)
// MODE 3: out f32  = resid + C + bias    (FC2)
template <int MODE>
__global__ __launch_bounds__(256) void gemm_bt(const __hip_bfloat16* __restrict__ A,
                                               const __hip_bfloat16* __restrict__ BT,
                                               const float* __restrict__ bias,
                                               const float* __restrict__ resid,
                                               void* __restrict__ outp,
                                               void* __restrict__ outp2,
                                               int N, int K) {
  __shared__ __hip_bfloat16 Als[128 * 32];
  __shared__ __hip_bfloat16 Bls[128 * 32];
  const int tid = threadIdx.x;
  const int w = tid >> 6, l = tid & 63;
  const int tile_n = blockIdx.x * 128;
  const int tile_m = blockIdx.y * 128;
  const int wm = (w >> 1) * 64, wn = (w & 1) * 64;

  f32x4 acc[4][4] = {};

  const int srow = w * 16 + (l >> 2);
  const int scol = (l & 3) * 8;
  const __hip_bfloat16* Ag = A  + (size_t)(tile_m + srow) * K + scol;
  const __hip_bfloat16* Bg = BT + (size_t)(tile_n + srow) * K + scol;
  __hip_bfloat16* AlsW = &Als[(w * 16) * 32];
  __hip_bfloat16* BlsW = &Bls[(w * 16) * 32];

  const int m_ = (l & 15);
  const int kq = (l >> 4) * 8;

  for (int k0 = 0; k0 < K; k0 += 32) {
    __builtin_amdgcn_global_load_lds(GLB_AS(Ag + k0),                 LDS_AS(AlsW),           16, 0, 0);
    __builtin_amdgcn_global_load_lds(GLB_AS(Ag + (size_t)64*K + k0),  LDS_AS(AlsW + 64*32),   16, 0, 0);
    __builtin_amdgcn_global_load_lds(GLB_AS(Bg + k0),                 LDS_AS(BlsW),           16, 0, 0);
    __builtin_amdgcn_global_load_lds(GLB_AS(Bg + (size_t)64*K + k0),  LDS_AS(BlsW + 64*32),   16, 0, 0);
    __syncthreads();
    bf16x8 af[4], bfr[4];
    #pragma unroll
    for (int mi = 0; mi < 4; mi++) af[mi]  = *(const bf16x8*)&Als[(wm + mi*16 + m_) * 32 + kq];
    #pragma unroll
    for (int ni = 0; ni < 4; ni++) bfr[ni] = *(const bf16x8*)&Bls[(wn + ni*16 + m_) * 32 + kq];
    #pragma unroll
    for (int mi = 0; mi < 4; mi++)
      #pragma unroll
      for (int ni = 0; ni < 4; ni++)
        acc[mi][ni] = mfma16(af[mi], bfr[ni], acc[mi][ni]);
    __syncthreads();
  }

  // epilogue: C/D layout col=lane&15, row=(lane>>4)*4+reg
  const int r0 = tile_m + wm + (l >> 4) * 4;
  const int c0 = tile_n + wn + m_;
  #pragma unroll
  for (int mi = 0; mi < 4; mi++) {
    #pragma unroll
    for (int r = 0; r < 4; r++) {
      const int row = r0 + mi * 16 + r;
      #pragma unroll
      for (int ni = 0; ni < 4; ni++) {
        const int col = c0 + ni * 16;
        float v = acc[mi][ni][r] + bias[col];
        if (MODE == 0) {
          if (tile_n < 2 * C_) {
            ((__hip_bfloat16*)outp)[(size_t)row * (2*C_) + col] = f2bf(v);
          } else {
            // vT[(b*1024 + dg)][t], dg = col-2048, b = row>>11, t = row&2047
            const int dg = col - 2 * C_;
            ((__hip_bfloat16*)outp2)[((size_t)((row >> 11) * 1024 + dg)) * T_ + (row & 2047)] = f2bf(v);
          }
        } else if (MODE == 1 || MODE == 3) {
          ((float*)outp)[(size_t)row * N + col] = resid[(size_t)row * N + col] + v;
        } else { // gelu, overflow-safe tanh via exp
          const float u = 0.7978845608028654f * (v + 0.044715f * v * v * v);
          const float e = __expf(2.0f * u);
          const float th = 1.0f - 2.0f / (e + 1.0f);
          ((__hip_bfloat16*)outp)[(size_t)row * N + col] = f2bf(v * (1.0f - 1.0f / (e + 1.0f)));
        }
      }
    }
  }
}

// ---------------- flash attention v2 (causal), register softmax ----------------
// qk: [B*T][2C] bf16 (Q cols 0..1023, K cols 1024..2047); vT: [B*NH*64][T] bf16
__global__ __launch_bounds__(256) void flash_attn(const __hip_bfloat16* __restrict__ qk,
                                                  const __hip_bfloat16* __restrict__ vT,
                                                  __hip_bfloat16* __restrict__ y) {
  const int qt = gridDim.x - 1 - blockIdx.x;   // longest blocks first
  const int bh = blockIdx.y;                   // 0..63
  const int b  = bh >> 4, h = bh & 15;
  const int tid = threadIdx.x, w = tid >> 6, l = tid & 63;
  const int q0 = qt * 64;
  const int m_ = l & 15, q_ = l >> 4;

  __shared__ __hip_bfloat16 Kls[64 * 72];
  __shared__ __hip_bfloat16 VTls[64 * 72];
  __shared__ __hip_bfloat16 Pls[64 * 72];

  // Q fragments (A layout), scaled by 1/8 * log2(e)  (exp2-space softmax)
  bf16x8 aq0, aq1;
  {
    const float qscale = 0.125f * 1.44269504088896f;
    const size_t qbase = ((size_t)b * T_ + q0 + w * 16 + m_) * (2 * C_) + h * 64;
    union { uint4 u; __hip_bfloat16 h8[8]; } t0, t1;
    t0.u = *(const uint4*)&qk[qbase + q_ * 8];
    t1.u = *(const uint4*)&qk[qbase + 32 + q_ * 8];
    __hip_bfloat16 a0[8], a1[8];
    #pragma unroll
    for (int j = 0; j < 8; j++) { a0[j] = f2bf(bf2f(t0.h8[j]) * qscale); a1[j] = f2bf(bf2f(t1.h8[j]) * qscale); }
    aq0 = *(const bf16x8*)a0; aq1 = *(const bf16x8*)a1;
  }

  float mst[4] = {-1e30f, -1e30f, -1e30f, -1e30f};
  float lst[4] = {0.f, 0.f, 0.f, 0.f};
  f32x4 accO[4] = {};

  const size_t kbase  = (size_t)b * T_ * (2 * C_) + C_ + h * 64;
  const size_t vtbase = (size_t)bh * 64 * T_;
  const int urow = tid >> 3;          // 0..31
  const int uc8  = (tid & 7) * 8;     // 0..56

  for (int kt = 0; kt <= qt; kt++) {
    __syncthreads();   // prev-iter LDS reads done before restaging
    {
      uint4 k0v = *(const uint4*)&qk[kbase + (size_t)(kt*64 + urow)      * (2*C_) + uc8];
      uint4 k1v = *(const uint4*)&qk[kbase + (size_t)(kt*64 + urow + 32) * (2*C_) + uc8];
      uint4 v0v = *(const uint4*)&vT[vtbase + (size_t)urow        * T_ + kt*64 + uc8];
      uint4 v1v = *(const uint4*)&vT[vtbase + (size_t)(urow + 32) * T_ + kt*64 + uc8];
      *(uint4*)&Kls [urow        * 72 + uc8] = k0v;
      *(uint4*)&Kls [(urow + 32) * 72 + uc8] = k1v;
      *(uint4*)&VTls[urow        * 72 + uc8] = v0v;
      *(uint4*)&VTls[(urow + 32) * 72 + uc8] = v1v;
    }
    __syncthreads();

    // S = Q K^T (wave w owns q-rows [w*16, w*16+16))
    f32x4 s[4];
    #pragma unroll
    for (int ni = 0; ni < 4; ni++) {
      bf16x8 bk0 = *(const bf16x8*)&Kls[(ni*16 + m_) * 72 + q_*8];
      bf16x8 bk1 = *(const bf16x8*)&Kls[(ni*16 + m_) * 72 + 32 + q_*8];
      f32x4 z = {};
      z = mfma16(aq0, bk0, z);
      s[ni] = mfma16(aq1, bk1, z);
    }
    // causal mask (same tile only)
    if (kt == qt) {
      #pragma unroll
      for (int ni = 0; ni < 4; ni++)
        #pragma unroll
        for (int r = 0; r < 4; r++)
          if (ni*16 + m_ > w*16 + q_*4 + r) s[ni][r] = -1e30f;
    }

    // row max across ni, then across the 16 lanes sharing each row
    float mx[4];
    #pragma unroll
    for (int r = 0; r < 4; r++)
      mx[r] = fmaxf(fmaxf(s[0][r], s[1][r]), fmaxf(s[2][r], s[3][r]));
    #pragma unroll
    for (int d = 1; d < 16; d <<= 1)
      #pragma unroll
      for (int r = 0; r < 4; r++)
        mx[r] = fmaxf(mx[r], __shfl_xor(mx[r], d, 64));

    float alpha[4];
    #pragma unroll
    for (int r = 0; r < 4; r++) {
      const float mn = fmaxf(mst[r], mx[r]);
      alpha[r] = exp2f(mst[r] - mn);
      mst[r] = mn;
    }
    #pragma unroll
    for (int ni = 0; ni < 4; ni++)
      #pragma unroll
      for (int r = 0; r < 4; r++)
        s[ni][r] = exp2f(s[ni][r] - mst[r]);
    float rs[4];
    #pragma unroll
    for (int r = 0; r < 4; r++)
      rs[r] = (s[0][r] + s[1][r]) + (s[2][r] + s[3][r]);
    #pragma unroll
    for (int d = 1; d < 16; d <<= 1)
      #pragma unroll
      for (int r = 0; r < 4; r++)
        rs[r] += __shfl_xor(rs[r], d, 64);
    #pragma unroll
    for (int r = 0; r < 4; r++)
      lst[r] = lst[r] * alpha[r] + rs[r];
    #pragma unroll
    for (int ni = 0; ni < 4; ni++)
      #pragma unroll
      for (int r = 0; r < 4; r++)
        accO[ni][r] *= alpha[r];

    // P: C layout -> LDS (bf16)
    #pragma unroll
    for (int ni = 0; ni < 4; ni++)
      #pragma unroll
      for (int r = 0; r < 4; r++)
        Pls[(w*16 + q_*4 + r) * 72 + ni*16 + m_] = f2bf(s[ni][r]);
    __syncthreads();

    // O += P V  (P read back in A layout)
    bf16x8 ap0 = *(const bf16x8*)&Pls[(w*16 + m_) * 72 + q_*8];
    bf16x8 ap1 = *(const bf16x8*)&Pls[(w*16 + m_) * 72 + 32 + q_*8];
    #pragma unroll
    for (int ni = 0; ni < 4; ni++) {
      bf16x8 bv0 = *(const bf16x8*)&VTls[(ni*16 + m_) * 72 + q_*8];
      bf16x8 bv1 = *(const bf16x8*)&VTls[(ni*16 + m_) * 72 + 32 + q_*8];
      accO[ni] = mfma16(ap0, bv0, accO[ni]);
      accO[ni] = mfma16(ap1, bv1, accO[ni]);
    }
  }

  // epilogue: y[b, q0+row, h*64 + col] = O / l
  const size_t ybase = ((size_t)b * T_ + q0) * C_ + h * 64;
  #pragma unroll
  for (int r = 0; r < 4; r++) {
    const int row = w*16 + q_*4 + r;
    const float linv = 1.0f / lst[r];
    #pragma unroll
    for (int ni = 0; ni < 4; ni++)
      y[ybase + (size_t)row * C_ + ni*16 + m_] = f2bf(accO[ni][r] * linv);
  }
}

// ---------------- launch ----------------
extern "C" void kernel_launch(void* const* d_in, const int* in_sizes, int n_in,
                              void* d_out, int out_size, void* d_ws, size_t ws_size,
                              hipStream_t stream) {
  const float* x      = (const float*)d_in[0];
  const float* ln1_g  = (const float*)d_in[1];
  const float* ln1_b  = (const float*)d_in[2];
  const float* w_attn = (const float*)d_in[3];
  const float* b_attn = (const float*)d_in[4];
  const float* w_proj = (const float*)d_in[5];
  const float* b_proj = (const float*)d_in[6];
  const float* ln2_g  = (const float*)d_in[7];
  const float* ln2_b  = (const float*)d_in[8];
  const float* w_fc   = (const float*)d_in[9];
  const float* b_fc   = (const float*)d_in[10];
  const float* w_fc2  = (const float*)d_in[11];
  const float* b_fc2  = (const float*)d_in[12];
  float* out = (float*)d_out;

  char* ws = (char*)d_ws;
  const size_t MB = 1024 * 1024;
  __hip_bfloat16* h      = (__hip_bfloat16*)(ws);                 // 16MB [0,16)
  __hip_bfloat16* qk     = (__hip_bfloat16*)(ws + 16*MB);         // 32MB [16,48)
  __hip_bfloat16* vT     = (__hip_bfloat16*)(ws + 48*MB);         // 16MB [48,64)
  __hip_bfloat16* y      = (__hip_bfloat16*)(ws + 64*MB);         // 16MB [64,80)
  float*          x2     = (float*)        (ws + 80*MB);          // 32MB [80,112)
  __hip_bfloat16* h2     = (__hip_bfloat16*)(ws + 64*MB);         // reuse y slot
  __hip_bfloat16* gbuf   = (__hip_bfloat16*)(ws);                 // 64MB reuse [0,64)
  __hip_bfloat16* wattnT = (__hip_bfloat16*)(ws + 112*MB);        // 6MB
  __hip_bfloat16* wprojT = (__hip_bfloat16*)(ws + 118*MB);        // 2MB
  __hip_bfloat16* wfcT   = (__hip_bfloat16*)(ws + 120*MB);        // 8MB
  __hip_bfloat16* wfc2T  = (__hip_bfloat16*)(ws + 128*MB);        // 8MB

  // weights: [K][N] fp32 -> [N][K] bf16
  transpose_bf16<<<dim3(3*C_/32, C_/32), 256, 0, stream>>>(w_attn, wattnT, C_, 3*C_);
  transpose_bf16<<<dim3(C_/32,  C_/32), 256, 0, stream>>>(w_proj, wprojT, C_, C_);
  transpose_bf16<<<dim3(FF_/32, C_/32), 256, 0, stream>>>(w_fc,   wfcT,   C_, FF_);
  transpose_bf16<<<dim3(C_/32, FF_/32), 256, 0, stream>>>(w_fc2,  wfc2T,  FF_, C_);

  // LN1
  ln_bf16<<<NT_, 256, 0, stream>>>(x, ln1_g, ln1_b, h);
  // QKV (Q,K -> qk packed [t][2C]; V -> vT [b*1024+dg][t])
  gemm_bt<0><<<dim3(3*C_/128, NT_/128), 256, 0, stream>>>(h, wattnT, b_attn, nullptr, qk, vT, 3*C_, C_);
  // attention
  flash_attn<<<dim3(T_/64, B_*NH_), 256, 0, stream>>>(qk, vT, y);
  // proj + residual -> x2 (fp32)
  gemm_bt<1><<<dim3(C_/128, NT_/128), 256, 0, stream>>>(y, wprojT, b_proj, x, x2, nullptr, C_, C_);
  // LN2
  ln_bf16<<<NT_, 256, 0, stream>>>(x2, ln2_g, ln2_b, h2);
  // FC + gelu
  gemm_bt<2><<<dim3(FF_/128, NT_/128), 256, 0, stream>>>(h2, wfcT, b_fc, nullptr, gbuf, nullptr, FF_, C_);
  // FC2 + residual -> out (fp32)
  gemm_bt<3><<<dim3(C_/128, NT_/128), 256, 0, stream>>>(gbuf, wfc2T, b_fc2, x2, out, nullptr, C_, FF_);
}

// Round 3
// 753.957 us; speedup vs baseline: 1.6495x; 1.0090x over previous
//
#include <hip/hip_runtime.h>
#include <hip/hip_bf16.h>

#define B_ 4
#define T_ 2048
#define C_ 1024
#define NH_ 16
#define FF_ 4096
#define NT_ (B_*T_)   // 8192 token rows

typedef short bf16x8 __attribute__((ext_vector_type(8)));
typedef float f32x4 __attribute__((ext_vector_type(4)));

#define LDS_AS(p) ((__attribute__((address_space(3))) uint32_t*)(p))
#define GLB_AS(p) ((const __attribute__((address_space(1))) uint32_t*)(p))

__device__ __forceinline__ float bf2f(__hip_bfloat16 v){ return __bfloat162float(v); }
__device__ __forceinline__ __hip_bfloat16 f2bf(float f){ return __float2bfloat16(f); }

__device__ __forceinline__ f32x4 mfma16(bf16x8 a, bf16x8 b, f32x4 c){
  return __builtin_amdgcn_mfma_f32_16x16x32_bf16(a, b, c, 0, 0, 0);
}

// ---------------- weight transpose + fp32->bf16 cast:  in[K][N] -> out[N][K] ----------------
__global__ __launch_bounds__(256) void transpose_bf16(const float* __restrict__ in,
                                                      __hip_bfloat16* __restrict__ out,
                                                      int K, int N) {
  __shared__ float tile[32][33];
  const int n0 = blockIdx.x * 32, k0 = blockIdx.y * 32;
  const int x = threadIdx.x & 31, y = threadIdx.x >> 5;   // y in 0..7
  #pragma unroll
  for (int i = 0; i < 4; i++)
    tile[y + 8*i][x] = in[(size_t)(k0 + y + 8*i) * N + n0 + x];
  __syncthreads();
  #pragma unroll
  for (int i = 0; i < 4; i++)
    out[(size_t)(n0 + y + 8*i) * K + k0 + x] = f2bf(tile[x][y + 8*i]);
}

// ---------------- LayerNorm fp32 -> bf16 (row = 1024) ----------------
__global__ __launch_bounds__(256) void ln_bf16(const float* __restrict__ x,
                                               const float* __restrict__ g,
                                               const float* __restrict__ b,
                                               __hip_bfloat16* __restrict__ out) {
  const int row = blockIdx.x;
  const int tid = threadIdx.x;
  float4 v = ((const float4*)(x + (size_t)row * C_))[tid];
  float s  = v.x + v.y + v.z + v.w;
  float s2 = v.x*v.x + v.y*v.y + v.z*v.z + v.w*v.w;
  #pragma unroll
  for (int off = 32; off > 0; off >>= 1) {
    s  += __shfl_down(s,  off, 64);
    s2 += __shfl_down(s2, off, 64);
  }
  __shared__ float red[8];
  const int w = tid >> 6, l = tid & 63;
  if (l == 0) { red[w] = s; red[4 + w] = s2; }
  __syncthreads();
  s  = red[0] + red[1] + red[2] + red[3];
  s2 = red[4] + red[5] + red[6] + red[7];
  const float mu   = s * (1.0f / C_);
  const float var  = s2 * (1.0f / C_) - mu * mu;
  const float rstd = rsqrtf(var + 1e-5f);
  float4 gv = ((const float4*)g)[tid];
  float4 bv = ((const float4*)b)[tid];
  ushort4 o;
  __hip_bfloat16 t;
  t = f2bf((v.x - mu) * rstd * gv.x + bv.x); o.x = *(unsigned short*)&t;
  t = f2bf((v.y - mu) * rstd * gv.y + bv.y); o.y = *(unsigned short*)&t;
  t = f2bf((v.z - mu) * rstd * gv.z + bv.z); o.z = *(unsigned short*)&t;
  t = f2bf((v.w - mu) * rstd * gv.w + bv.w); o.w = *(unsigned short*)&t;
  ((ushort4*)out)[(size_t)row * (C_/4) + tid] = o;
}

// ---------------- shared MFMA GEMM:  C[M][N] = A[M][K] * BT[N][K]^T  + epilogue ----------------
// MODE 0: QKV. cols <2048 -> bf16 qk[row][col] (ld 2048); cols >=2048 -> bf16 vT[b,dg,t]
// MODE 1: out f32  = resid + C + bias    (proj)
// MODE 2: out bf16 = gelu(C + bias)      (FC)
// MODE 3: out f32  = resid + C + bias    (FC2)
template <int MODE>
__global__ __launch_bounds__(256) void gemm_bt(const __hip_bfloat16* __restrict__ A,
                                               const __hip_bfloat16* __restrict__ BT,
                                               const float* __restrict__ bias,
                                               const float* __restrict__ resid,
                                               void* __restrict__ outp,
                                               void* __restrict__ outp2,
                                               int N, int K) {
  __shared__ __hip_bfloat16 Als[128 * 32];
  __shared__ __hip_bfloat16 Bls[128 * 32];
  const int tid = threadIdx.x;
  const int w = tid >> 6, l = tid & 63;
  const int tile_n = blockIdx.x * 128;
  const int tile_m = blockIdx.y * 128;
  const int wm = (w >> 1) * 64, wn = (w & 1) * 64;

  f32x4 acc[4][4] = {};

  const int srow = w * 16 + (l >> 2);
  const int scol = (l & 3) * 8;
  const __hip_bfloat16* Ag = A  + (size_t)(tile_m + srow) * K + scol;
  const __hip_bfloat16* Bg = BT + (size_t)(tile_n + srow) * K + scol;
  __hip_bfloat16* AlsW = &Als[(w * 16) * 32];
  __hip_bfloat16* BlsW = &Bls[(w * 16) * 32];

  const int m_ = (l & 15);
  const int kq = (l >> 4) * 8;

  for (int k0 = 0; k0 < K; k0 += 32) {
    __builtin_amdgcn_global_load_lds(GLB_AS(Ag + k0),                 LDS_AS(AlsW),           16, 0, 0);
    __builtin_amdgcn_global_load_lds(GLB_AS(Ag + (size_t)64*K + k0),  LDS_AS(AlsW + 64*32),   16, 0, 0);
    __builtin_amdgcn_global_load_lds(GLB_AS(Bg + k0),                 LDS_AS(BlsW),           16, 0, 0);
    __builtin_amdgcn_global_load_lds(GLB_AS(Bg + (size_t)64*K + k0),  LDS_AS(BlsW + 64*32),   16, 0, 0);
    __syncthreads();
    bf16x8 af[4], bfr[4];
    #pragma unroll
    for (int mi = 0; mi < 4; mi++) af[mi]  = *(const bf16x8*)&Als[(wm + mi*16 + m_) * 32 + kq];
    #pragma unroll
    for (int ni = 0; ni < 4; ni++) bfr[ni] = *(const bf16x8*)&Bls[(wn + ni*16 + m_) * 32 + kq];
    #pragma unroll
    for (int mi = 0; mi < 4; mi++)
      #pragma unroll
      for (int ni = 0; ni < 4; ni++)
        acc[mi][ni] = mfma16(af[mi], bfr[ni], acc[mi][ni]);
    __syncthreads();
  }

  // epilogue: C/D layout col=lane&15, row=(lane>>4)*4+reg
  const int r0 = tile_m + wm + (l >> 4) * 4;
  const int c0 = tile_n + wn + m_;
  #pragma unroll
  for (int mi = 0; mi < 4; mi++) {
    #pragma unroll
    for (int r = 0; r < 4; r++) {
      const int row = r0 + mi * 16 + r;
      #pragma unroll
      for (int ni = 0; ni < 4; ni++) {
        const int col = c0 + ni * 16;
        float v = acc[mi][ni][r] + bias[col];
        if (MODE == 0) {
          if (tile_n < 2 * C_) {
            ((__hip_bfloat16*)outp)[(size_t)row * (2*C_) + col] = f2bf(v);
          } else {
            // vT[(b*1024 + dg)][t], dg = col-2048, b = row>>11, t = row&2047
            const int dg = col - 2 * C_;
            ((__hip_bfloat16*)outp2)[((size_t)((row >> 11) * 1024 + dg)) * T_ + (row & 2047)] = f2bf(v);
          }
        } else if (MODE == 1 || MODE == 3) {
          ((float*)outp)[(size_t)row * N + col] = resid[(size_t)row * N + col] + v;
        } else { // gelu
          const float u = 0.7978845608028654f * (v + 0.044715f * v * v * v);
          const float e = __expf(2.0f * u);
          ((__hip_bfloat16*)outp)[(size_t)row * N + col] = f2bf(v * (1.0f - 1.0f / (e + 1.0f)));
        }
      }
    }
  }
}

// ---------------- flash attention v3 (causal) ----------------
// 128-row Q tile per block, double-buffered K/V staging via global_load_lds with
// XOR-swizzled LDS layout (conflict-free, pad-free), register online-softmax,
// wave-local P round-trip, ONE barrier per k-tile.
// qk: [B*T][2C] bf16 (Q cols 0..1023, K cols 1024..2047); vT: [B*NH*64][T] bf16
__global__ __launch_bounds__(256) void flash_attn(const __hip_bfloat16* __restrict__ qk,
                                                  const __hip_bfloat16* __restrict__ vT,
                                                  __hip_bfloat16* __restrict__ y) {
  const int qt = gridDim.x - 1 - blockIdx.x;   // longest blocks first
  const int bh = blockIdx.y;                   // 0..63
  const int b  = bh >> 4, h = bh & 15;
  const int tid = threadIdx.x, w = tid >> 6, l = tid & 63;
  const int q0 = qt * 128;
  const int m_ = l & 15, q_ = l >> 4;

  __shared__ __hip_bfloat16 Kls[2][64 * 64];   // [key][d], col8 swizzled by row&7
  __shared__ __hip_bfloat16 VTls[2][64 * 64];  // [d][key], col8 swizzled by row&7
  __shared__ __hip_bfloat16 Pls[128 * 72];     // wave-local P, padded stride

  // --- Q fragments (A layout): 2 m-frags x 2 k-halves, scaled by 1/8*log2(e) ---
  bf16x8 aq[2][2];
  {
    const float qscale = 0.125f * 1.44269504088896f;
    #pragma unroll
    for (int mf = 0; mf < 2; mf++) {
      const size_t qbase = ((size_t)b * T_ + q0 + w*32 + mf*16 + m_) * (2*C_) + h*64;
      #pragma unroll
      for (int kh = 0; kh < 2; kh++) {
        union { uint4 u; __hip_bfloat16 h8[8]; } t;
        t.u = *(const uint4*)&qk[qbase + kh*32 + q_*8];
        __hip_bfloat16 a[8];
        #pragma unroll
        for (int j = 0; j < 8; j++) a[j] = f2bf(bf2f(t.h8[j]) * qscale);
        aq[mf][kh] = *(const bf16x8*)a;
      }
    }
  }

  float mst[2][4], lst[2][4];
  #pragma unroll
  for (int mf = 0; mf < 2; mf++)
    #pragma unroll
    for (int r = 0; r < 4; r++) { mst[mf][r] = -1e30f; lst[mf][r] = 0.0f; }
  f32x4 accO[2][4] = {};

  const size_t kgbase = (size_t)b * T_ * (2*C_) + C_ + h*64;  // + t*(2C) + d
  const size_t vgbase = (size_t)bh * 64 * T_;                 // + d*T + t
  const int sr = l >> 3;      // 0..7: row within 8-row staging group
  const int sc = l & 7;       // LDS 16B slot within row
  const int ktmax = 2*qt + 1;

  // stage k-tile kt_ into buffer buf (wave w covers rows [w*16, w*16+16))
  #define STAGE_KV(kt_, buf)                                                              \
    _Pragma("unroll")                                                                     \
    for (int i = 0; i < 2; i++) {                                                         \
      const int r_ = w*16 + i*8 + sr;                                                     \
      const int c8_ = sc ^ (r_ & 7);                                                      \
      __builtin_amdgcn_global_load_lds(                                                   \
          GLB_AS(qk + kgbase + (size_t)((kt_)*64 + r_) * (2*C_) + c8_*8),                 \
          LDS_AS(&Kls[buf][(w*16 + i*8) * 64]), 16, 0, 0);                                \
      __builtin_amdgcn_global_load_lds(                                                   \
          GLB_AS(vT + vgbase + (size_t)r_ * T_ + (kt_)*64 + c8_*8),                       \
          LDS_AS(&VTls[buf][(w*16 + i*8) * 64]), 16, 0, 0);                               \
    }

  STAGE_KV(0, 0)
  __syncthreads();

  for (int kt = 0; kt <= ktmax; kt++) {
    const int cur = kt & 1;
    if (kt < ktmax) { STAGE_KV(kt+1, cur^1) }

    // --- S = Q K^T ---
    f32x4 s[2][4];
    #pragma unroll
    for (int ni = 0; ni < 4; ni++) {
      const int r = ni*16 + m_;
      bf16x8 bk0 = *(const bf16x8*)&Kls[cur][r*64 + ((q_     ^ (r & 7)) * 8)];
      bf16x8 bk1 = *(const bf16x8*)&Kls[cur][r*64 + (((4+q_) ^ (r & 7)) * 8)];
      #pragma unroll
      for (int mf = 0; mf < 2; mf++) {
        f32x4 z = {};
        z = mfma16(aq[mf][0], bk0, z);
        s[mf][ni] = mfma16(aq[mf][1], bk1, z);
      }
    }

    // --- causal mask (only last two k-tiles interact with the diagonal) ---
    if (kt >= 2*qt) {
      #pragma unroll
      for (int mf = 0; mf < 2; mf++) {
        const int qrow = q0 + w*32 + mf*16 + q_*4;
        #pragma unroll
        for (int ni = 0; ni < 4; ni++) {
          const int kcol = kt*64 + ni*16 + m_;
          #pragma unroll
          for (int r = 0; r < 4; r++)
            if (kcol > qrow + r) s[mf][ni][r] = -1e30f;
        }
      }
    }

    // --- online softmax (exp2 space), per m-frag ---
    #pragma unroll
    for (int mf = 0; mf < 2; mf++) {
      float mx[4];
      #pragma unroll
      for (int r = 0; r < 4; r++)
        mx[r] = fmaxf(fmaxf(s[mf][0][r], s[mf][1][r]), fmaxf(s[mf][2][r], s[mf][3][r]));
      #pragma unroll
      for (int d = 1; d < 16; d <<= 1)
        #pragma unroll
        for (int r = 0; r < 4; r++)
          mx[r] = fmaxf(mx[r], __shfl_xor(mx[r], d, 64));
      float alpha[4];
      #pragma unroll
      for (int r = 0; r < 4; r++) {
        const float mn = fmaxf(mst[mf][r], mx[r]);
        alpha[r] = exp2f(mst[mf][r] - mn);
        mst[mf][r] = mn;
      }
      #pragma unroll
      for (int ni = 0; ni < 4; ni++)
        #pragma unroll
        for (int r = 0; r < 4; r++)
          s[mf][ni][r] = exp2f(s[mf][ni][r] - mst[mf][r]);
      float rs[4];
      #pragma unroll
      for (int r = 0; r < 4; r++)
        rs[r] = (s[mf][0][r] + s[mf][1][r]) + (s[mf][2][r] + s[mf][3][r]);
      #pragma unroll
      for (int d = 1; d < 16; d <<= 1)
        #pragma unroll
        for (int r = 0; r < 4; r++)
          rs[r] += __shfl_xor(rs[r], d, 64);
      #pragma unroll
      for (int r = 0; r < 4; r++)
        lst[mf][r] = lst[mf][r] * alpha[r] + rs[r];
      #pragma unroll
      for (int ni = 0; ni < 4; ni++)
        #pragma unroll
        for (int r = 0; r < 4; r++)
          accO[mf][ni][r] *= alpha[r];
      // P: C layout -> wave-local LDS band
      #pragma unroll
      for (int ni = 0; ni < 4; ni++)
        #pragma unroll
        for (int r = 0; r < 4; r++)
          Pls[(w*32 + mf*16 + q_*4 + r) * 72 + ni*16 + m_] = f2bf(s[mf][ni][r]);
    }

    // --- O += P V (P read back in A layout; wave-local, no barrier) ---
    bf16x8 ap[2][2];
    #pragma unroll
    for (int mf = 0; mf < 2; mf++) {
      ap[mf][0] = *(const bf16x8*)&Pls[(w*32 + mf*16 + m_) * 72 + q_*8];
      ap[mf][1] = *(const bf16x8*)&Pls[(w*32 + mf*16 + m_) * 72 + 32 + q_*8];
    }
    #pragma unroll
    for (int ni = 0; ni < 4; ni++) {
      const int r = ni*16 + m_;
      bf16x8 bv0 = *(const bf16x8*)&VTls[cur][r*64 + ((q_     ^ (r & 7)) * 8)];
      bf16x8 bv1 = *(const bf16x8*)&VTls[cur][r*64 + (((4+q_) ^ (r & 7)) * 8)];
      #pragma unroll
      for (int mf = 0; mf < 2; mf++) {
        accO[mf][ni] = mfma16(ap[mf][0], bv0, accO[mf][ni]);
        accO[mf][ni] = mfma16(ap[mf][1], bv1, accO[mf][ni]);
      }
    }

    __syncthreads();  // staging of kt+1 drained (vmcnt0) + LDS reads of cur done
  }
  #undef STAGE_KV

  // epilogue: y[b, q0+row, h*64 + col] = O / l
  const size_t ybase = ((size_t)b * T_ + q0) * C_ + h*64;
  #pragma unroll
  for (int mf = 0; mf < 2; mf++) {
    #pragma unroll
    for (int r = 0; r < 4; r++) {
      const int row = w*32 + mf*16 + q_*4 + r;
      const float linv = 1.0f / lst[mf][r];
      #pragma unroll
      for (int ni = 0; ni < 4; ni++)
        y[ybase + (size_t)row * C_ + ni*16 + m_] = f2bf(accO[mf][ni][r] * linv);
    }
  }
}

// ---------------- launch ----------------
extern "C" void kernel_launch(void* const* d_in, const int* in_sizes, int n_in,
                              void* d_out, int out_size, void* d_ws, size_t ws_size,
                              hipStream_t stream) {
  const float* x      = (const float*)d_in[0];
  const float* ln1_g  = (const float*)d_in[1];
  const float* ln1_b  = (const float*)d_in[2];
  const float* w_attn = (const float*)d_in[3];
  const float* b_attn = (const float*)d_in[4];
  const float* w_proj = (const float*)d_in[5];
  const float* b_proj = (const float*)d_in[6];
  const float* ln2_g  = (const float*)d_in[7];
  const float* ln2_b  = (const float*)d_in[8];
  const float* w_fc   = (const float*)d_in[9];
  const float* b_fc   = (const float*)d_in[10];
  const float* w_fc2  = (const float*)d_in[11];
  const float* b_fc2  = (const float*)d_in[12];
  float* out = (float*)d_out;

  char* ws = (char*)d_ws;
  const size_t MB = 1024 * 1024;
  __hip_bfloat16* h      = (__hip_bfloat16*)(ws);                 // 16MB [0,16)
  __hip_bfloat16* qk     = (__hip_bfloat16*)(ws + 16*MB);         // 32MB [16,48)
  __hip_bfloat16* vT     = (__hip_bfloat16*)(ws + 48*MB);         // 16MB [48,64)
  __hip_bfloat16* y      = (__hip_bfloat16*)(ws + 64*MB);         // 16MB [64,80)
  float*          x2     = (float*)        (ws + 80*MB);          // 32MB [80,112)
  __hip_bfloat16* h2     = (__hip_bfloat16*)(ws + 64*MB);         // reuse y slot
  __hip_bfloat16* gbuf   = (__hip_bfloat16*)(ws);                 // 64MB reuse [0,64)
  __hip_bfloat16* wattnT = (__hip_bfloat16*)(ws + 112*MB);        // 6MB
  __hip_bfloat16* wprojT = (__hip_bfloat16*)(ws + 118*MB);        // 2MB
  __hip_bfloat16* wfcT   = (__hip_bfloat16*)(ws + 120*MB);        // 8MB
  __hip_bfloat16* wfc2T  = (__hip_bfloat16*)(ws + 128*MB);        // 8MB

  // weights: [K][N] fp32 -> [N][K] bf16
  transpose_bf16<<<dim3(3*C_/32, C_/32), 256, 0, stream>>>(w_attn, wattnT, C_, 3*C_);
  transpose_bf16<<<dim3(C_/32,  C_/32), 256, 0, stream>>>(w_proj, wprojT, C_, C_);
  transpose_bf16<<<dim3(FF_/32, C_/32), 256, 0, stream>>>(w_fc,   wfcT,   C_, FF_);
  transpose_bf16<<<dim3(C_/32, FF_/32), 256, 0, stream>>>(w_fc2,  wfc2T,  FF_, C_);

  // LN1
  ln_bf16<<<NT_, 256, 0, stream>>>(x, ln1_g, ln1_b, h);
  // QKV (Q,K -> qk packed [t][2C]; V -> vT [b*1024+dg][t])
  gemm_bt<0><<<dim3(3*C_/128, NT_/128), 256, 0, stream>>>(h, wattnT, b_attn, nullptr, qk, vT, 3*C_, C_);
  // attention (128-row Q tiles)
  flash_attn<<<dim3(T_/128, B_*NH_), 256, 0, stream>>>(qk, vT, y);
  // proj + residual -> x2 (fp32)
  gemm_bt<1><<<dim3(C_/128, NT_/128), 256, 0, stream>>>(y, wprojT, b_proj, x, x2, nullptr, C_, C_);
  // LN2
  ln_bf16<<<NT_, 256, 0, stream>>>(x2, ln2_g, ln2_b, h2);
  // FC + gelu
  gemm_bt<2><<<dim3(FF_/128, NT_/128), 256, 0, stream>>>(h2, wfcT, b_fc, nullptr, gbuf, nullptr, FF_, C_);
  // FC2 + residual -> out (fp32)
  gemm_bt<3><<<dim3(C_/128, NT_/128), 256, 0, stream>>>(gbuf, wfc2T, b_fc2, x2, out, nullptr, C_, FF_);
}

// Round 4
// 739.974 us; speedup vs baseline: 1.6807x; 1.0189x over previous
//
#include <hip/hip_runtime.h>
#include <hip/hip_bf16.h>

#define B_ 4
#define T_ 2048
#define C_ 1024
#define NH_ 16
#define FF_ 4096
#define NT_ (B_*T_)   // 8192 token rows

typedef short bf16x8 __attribute__((ext_vector_type(8)));
typedef float f32x4 __attribute__((ext_vector_type(4)));

#define LDS_AS(p) ((__attribute__((address_space(3))) uint32_t*)(p))
#define GLB_AS(p) ((const __attribute__((address_space(1))) uint32_t*)(p))

__device__ __forceinline__ float bf2f(__hip_bfloat16 v){ return __bfloat162float(v); }
__device__ __forceinline__ __hip_bfloat16 f2bf(float f){ return __float2bfloat16(f); }

__device__ __forceinline__ f32x4 mfma16(bf16x8 a, bf16x8 b, f32x4 c){
  return __builtin_amdgcn_mfma_f32_16x16x32_bf16(a, b, c, 0, 0, 0);
}

// ---------------- weight transpose + fp32->bf16 cast:  in[K][N] -> out[N][K] ----------------
__global__ __launch_bounds__(256) void transpose_bf16(const float* __restrict__ in,
                                                      __hip_bfloat16* __restrict__ out,
                                                      int K, int N) {
  __shared__ float tile[32][33];
  const int n0 = blockIdx.x * 32, k0 = blockIdx.y * 32;
  const int x = threadIdx.x & 31, y = threadIdx.x >> 5;   // y in 0..7
  #pragma unroll
  for (int i = 0; i < 4; i++)
    tile[y + 8*i][x] = in[(size_t)(k0 + y + 8*i) * N + n0 + x];
  __syncthreads();
  #pragma unroll
  for (int i = 0; i < 4; i++)
    out[(size_t)(n0 + y + 8*i) * K + k0 + x] = f2bf(tile[x][y + 8*i]);
}

// ---------------- LayerNorm fp32 -> bf16 (row = 1024) ----------------
__global__ __launch_bounds__(256) void ln_bf16(const float* __restrict__ x,
                                               const float* __restrict__ g,
                                               const float* __restrict__ b,
                                               __hip_bfloat16* __restrict__ out) {
  const int row = blockIdx.x;
  const int tid = threadIdx.x;
  float4 v = ((const float4*)(x + (size_t)row * C_))[tid];
  float s  = v.x + v.y + v.z + v.w;
  float s2 = v.x*v.x + v.y*v.y + v.z*v.z + v.w*v.w;
  #pragma unroll
  for (int off = 32; off > 0; off >>= 1) {
    s  += __shfl_down(s,  off, 64);
    s2 += __shfl_down(s2, off, 64);
  }
  __shared__ float red[8];
  const int w = tid >> 6, l = tid & 63;
  if (l == 0) { red[w] = s; red[4 + w] = s2; }
  __syncthreads();
  s  = red[0] + red[1] + red[2] + red[3];
  s2 = red[4] + red[5] + red[6] + red[7];
  const float mu   = s * (1.0f / C_);
  const float var  = s2 * (1.0f / C_) - mu * mu;
  const float rstd = rsqrtf(var + 1e-5f);
  float4 gv = ((const float4*)g)[tid];
  float4 bv = ((const float4*)b)[tid];
  ushort4 o;
  __hip_bfloat16 t;
  t = f2bf((v.x - mu) * rstd * gv.x + bv.x); o.x = *(unsigned short*)&t;
  t = f2bf((v.y - mu) * rstd * gv.y + bv.y); o.y = *(unsigned short*)&t;
  t = f2bf((v.z - mu) * rstd * gv.z + bv.z); o.z = *(unsigned short*)&t;
  t = f2bf((v.w - mu) * rstd * gv.w + bv.w); o.w = *(unsigned short*)&t;
  ((ushort4*)out)[(size_t)row * (C_/4) + tid] = o;
}

// ---------------- shared MFMA GEMM:  C[M][N] = A[M][K] * BT[N][K]^T  + epilogue ----------------
// MODE 0: QKV. cols <2048 -> bf16 qk[row][col] (ld 2048); cols >=2048 -> bf16 vT[b,dg,t]
// MODE 1: out f32  = resid + C + bias    (proj)
// MODE 2: out bf16 = gelu(C + bias)      (FC)
// MODE 3: out f32  = resid + C + bias    (FC2)
template <int MODE>
__global__ __launch_bounds__(256) void gemm_bt(const __hip_bfloat16* __restrict__ A,
                                               const __hip_bfloat16* __restrict__ BT,
                                               const float* __restrict__ bias,
                                               const float* __restrict__ resid,
                                               void* __restrict__ outp,
                                               void* __restrict__ outp2,
                                               int N, int K) {
  __shared__ __hip_bfloat16 Als[128 * 32];
  __shared__ __hip_bfloat16 Bls[128 * 32];
  const int tid = threadIdx.x;
  const int w = tid >> 6, l = tid & 63;
  const int tile_n = blockIdx.x * 128;
  const int tile_m = blockIdx.y * 128;
  const int wm = (w >> 1) * 64, wn = (w & 1) * 64;

  f32x4 acc[4][4] = {};

  const int srow = w * 16 + (l >> 2);
  const int scol = (l & 3) * 8;
  const __hip_bfloat16* Ag = A  + (size_t)(tile_m + srow) * K + scol;
  const __hip_bfloat16* Bg = BT + (size_t)(tile_n + srow) * K + scol;
  __hip_bfloat16* AlsW = &Als[(w * 16) * 32];
  __hip_bfloat16* BlsW = &Bls[(w * 16) * 32];

  const int m_ = (l & 15);
  const int kq = (l >> 4) * 8;

  for (int k0 = 0; k0 < K; k0 += 32) {
    __builtin_amdgcn_global_load_lds(GLB_AS(Ag + k0),                 LDS_AS(AlsW),           16, 0, 0);
    __builtin_amdgcn_global_load_lds(GLB_AS(Ag + (size_t)64*K + k0),  LDS_AS(AlsW + 64*32),   16, 0, 0);
    __builtin_amdgcn_global_load_lds(GLB_AS(Bg + k0),                 LDS_AS(BlsW),           16, 0, 0);
    __builtin_amdgcn_global_load_lds(GLB_AS(Bg + (size_t)64*K + k0),  LDS_AS(BlsW + 64*32),   16, 0, 0);
    __syncthreads();
    bf16x8 af[4], bfr[4];
    #pragma unroll
    for (int mi = 0; mi < 4; mi++) af[mi]  = *(const bf16x8*)&Als[(wm + mi*16 + m_) * 32 + kq];
    #pragma unroll
    for (int ni = 0; ni < 4; ni++) bfr[ni] = *(const bf16x8*)&Bls[(wn + ni*16 + m_) * 32 + kq];
    #pragma unroll
    for (int mi = 0; mi < 4; mi++)
      #pragma unroll
      for (int ni = 0; ni < 4; ni++)
        acc[mi][ni] = mfma16(af[mi], bfr[ni], acc[mi][ni]);
    __syncthreads();
  }

  // epilogue: C/D layout col=lane&15, row=(lane>>4)*4+reg
  const int r0 = tile_m + wm + (l >> 4) * 4;
  const int c0 = tile_n + wn + m_;
  #pragma unroll
  for (int mi = 0; mi < 4; mi++) {
    #pragma unroll
    for (int r = 0; r < 4; r++) {
      const int row = r0 + mi * 16 + r;
      #pragma unroll
      for (int ni = 0; ni < 4; ni++) {
        const int col = c0 + ni * 16;
        float v = acc[mi][ni][r] + bias[col];
        if (MODE == 0) {
          if (tile_n < 2 * C_) {
            ((__hip_bfloat16*)outp)[(size_t)row * (2*C_) + col] = f2bf(v);
          } else {
            // vT[(b*1024 + dg)][t], dg = col-2048, b = row>>11, t = row&2047
            const int dg = col - 2 * C_;
            ((__hip_bfloat16*)outp2)[((size_t)((row >> 11) * 1024 + dg)) * T_ + (row & 2047)] = f2bf(v);
          }
        } else if (MODE == 1 || MODE == 3) {
          ((float*)outp)[(size_t)row * N + col] = resid[(size_t)row * N + col] + v;
        } else { // gelu
          const float u = 0.7978845608028654f * (v + 0.044715f * v * v * v);
          const float e = __expf(2.0f * u);
          ((__hip_bfloat16*)outp)[(size_t)row * N + col] = f2bf(v * (1.0f - 1.0f / (e + 1.0f)));
        }
      }
    }
  }
}

// ---------------- flash attention v4 (causal) ----------------
// NO barriers, NO K/V LDS: each wave gathers K/V MFMA fragments directly from
// global (perfect 128B-line efficiency; L1/L2 serve the reuse). Fixed-max
// softmax (m=0): p = exp2(s), Sum(p) accumulated per-lane, reduced once at the
// epilogue. P goes C-layout -> A-layout via a wave-local LDS round-trip.
// qk: [B*T][2C] bf16 (Q cols 0..1023, K cols 1024..2047); vT: [B*NH*64][T] bf16
__global__ __launch_bounds__(256) void flash_attn(const __hip_bfloat16* __restrict__ qk,
                                                  const __hip_bfloat16* __restrict__ vT,
                                                  __hip_bfloat16* __restrict__ y) {
  const int qt = gridDim.x - 1 - blockIdx.x;   // longest blocks first
  const int bh = blockIdx.y;                   // 0..63
  const int b  = bh >> 4, h = bh & 15;
  const int tid = threadIdx.x, w = tid >> 6, l = tid & 63;
  const int q0 = qt * 128;
  const int m_ = l & 15, q_ = l >> 4;

  __shared__ __hip_bfloat16 Pls[128 * 76];   // wave-local bands, stride 76 (bank-spread)

  // --- Q fragments (A layout): 2 m-frags x 2 k-halves, scaled by 1/8*log2(e) ---
  bf16x8 aq[2][2];
  {
    const float qscale = 0.125f * 1.44269504088896f;
    #pragma unroll
    for (int mf = 0; mf < 2; mf++) {
      const size_t qbase = ((size_t)b * T_ + q0 + w*32 + mf*16 + m_) * (2*C_) + h*64;
      #pragma unroll
      for (int kh = 0; kh < 2; kh++) {
        union { uint4 u; __hip_bfloat16 h8[8]; } t;
        t.u = *(const uint4*)&qk[qbase + kh*32 + q_*8];
        __hip_bfloat16 a[8];
        #pragma unroll
        for (int j = 0; j < 8; j++) a[j] = f2bf(bf2f(t.h8[j]) * qscale);
        aq[mf][kh] = *(const bf16x8*)a;
      }
    }
  }

  f32x4 accO[2][4] = {};
  float lsum[2][4] = {{0.f,0.f,0.f,0.f},{0.f,0.f,0.f,0.f}};

  const size_t kgbase = (size_t)b * T_ * (2*C_) + C_ + h*64;  // + t*(2C) + d
  const size_t vgbase = (size_t)bh * 64 * T_;                 // + d*T + t
  const int ktmax = 2*qt + 1;

  for (int kt = 0; kt <= ktmax; kt++) {
    // --- direct global->register K and V fragments (B layout) ---
    bf16x8 bk[4][2], bv[4][2];
    #pragma unroll
    for (int ni = 0; ni < 4; ni++) {
      const __hip_bfloat16* kp = qk + kgbase + (size_t)(kt*64 + ni*16 + m_) * (2*C_);
      const __hip_bfloat16* vp = vT + vgbase + (size_t)(ni*16 + m_) * T_ + kt*64;
      union { uint4 u; bf16x8 f; } t0, t1, t2, t3;
      t0.u = *(const uint4*)(kp + q_*8);
      t1.u = *(const uint4*)(kp + 32 + q_*8);
      t2.u = *(const uint4*)(vp + q_*8);
      t3.u = *(const uint4*)(vp + 32 + q_*8);
      bk[ni][0] = t0.f; bk[ni][1] = t1.f;
      bv[ni][0] = t2.f; bv[ni][1] = t3.f;
    }

    // --- S = Q K^T ---
    f32x4 s[2][4];
    #pragma unroll
    for (int ni = 0; ni < 4; ni++)
      #pragma unroll
      for (int mf = 0; mf < 2; mf++) {
        f32x4 z = {};
        z = mfma16(aq[mf][0], bk[ni][0], z);
        s[mf][ni] = mfma16(aq[mf][1], bk[ni][1], z);
      }

    // --- causal mask (only last two k-tiles touch the diagonal) ---
    if (kt >= 2*qt) {
      #pragma unroll
      for (int mf = 0; mf < 2; mf++) {
        const int qrow = q0 + w*32 + mf*16 + q_*4;
        #pragma unroll
        for (int ni = 0; ni < 4; ni++) {
          const int kcol = kt*64 + ni*16 + m_;
          #pragma unroll
          for (int r = 0; r < 4; r++)
            if (kcol > qrow + r) s[mf][ni][r] = -1e30f;
        }
      }
    }

    // --- p = exp2(s); accumulate row-sum per lane; stage P to wave-local LDS ---
    #pragma unroll
    for (int mf = 0; mf < 2; mf++) {
      #pragma unroll
      for (int ni = 0; ni < 4; ni++)
        #pragma unroll
        for (int r = 0; r < 4; r++)
          s[mf][ni][r] = exp2f(s[mf][ni][r]);
      #pragma unroll
      for (int r = 0; r < 4; r++)
        lsum[mf][r] += (s[mf][0][r] + s[mf][1][r]) + (s[mf][2][r] + s[mf][3][r]);
      #pragma unroll
      for (int ni = 0; ni < 4; ni++)
        #pragma unroll
        for (int r = 0; r < 4; r++)
          Pls[(w*32 + mf*16 + q_*4 + r) * 76 + ni*16 + m_] = f2bf(s[mf][ni][r]);
    }

    // --- O += P V (P read back in A layout; wave-local => only lgkmcnt waits) ---
    bf16x8 ap[2][2];
    #pragma unroll
    for (int mf = 0; mf < 2; mf++) {
      ap[mf][0] = *(const bf16x8*)&Pls[(w*32 + mf*16 + m_) * 76 + q_*8];
      ap[mf][1] = *(const bf16x8*)&Pls[(w*32 + mf*16 + m_) * 76 + 32 + q_*8];
    }
    #pragma unroll
    for (int ni = 0; ni < 4; ni++)
      #pragma unroll
      for (int mf = 0; mf < 2; mf++) {
        accO[mf][ni] = mfma16(ap[mf][0], bv[ni][0], accO[mf][ni]);
        accO[mf][ni] = mfma16(ap[mf][1], bv[ni][1], accO[mf][ni]);
      }
  }

  // --- epilogue: reduce Sum(p) across the 16 lanes sharing each row, store O/l ---
  #pragma unroll
  for (int mf = 0; mf < 2; mf++)
    #pragma unroll
    for (int r = 0; r < 4; r++) {
      #pragma unroll
      for (int d = 1; d < 16; d <<= 1)
        lsum[mf][r] += __shfl_xor(lsum[mf][r], d, 64);
    }

  const size_t ybase = ((size_t)b * T_ + q0) * C_ + h*64;
  #pragma unroll
  for (int mf = 0; mf < 2; mf++) {
    #pragma unroll
    for (int r = 0; r < 4; r++) {
      const int row = w*32 + mf*16 + q_*4 + r;
      const float linv = 1.0f / lsum[mf][r];
      #pragma unroll
      for (int ni = 0; ni < 4; ni++)
        y[ybase + (size_t)row * C_ + ni*16 + m_] = f2bf(accO[mf][ni][r] * linv);
    }
  }
}

// ---------------- launch ----------------
extern "C" void kernel_launch(void* const* d_in, const int* in_sizes, int n_in,
                              void* d_out, int out_size, void* d_ws, size_t ws_size,
                              hipStream_t stream) {
  const float* x      = (const float*)d_in[0];
  const float* ln1_g  = (const float*)d_in[1];
  const float* ln1_b  = (const float*)d_in[2];
  const float* w_attn = (const float*)d_in[3];
  const float* b_attn = (const float*)d_in[4];
  const float* w_proj = (const float*)d_in[5];
  const float* b_proj = (const float*)d_in[6];
  const float* ln2_g  = (const float*)d_in[7];
  const float* ln2_b  = (const float*)d_in[8];
  const float* w_fc   = (const float*)d_in[9];
  const float* b_fc   = (const float*)d_in[10];
  const float* w_fc2  = (const float*)d_in[11];
  const float* b_fc2  = (const float*)d_in[12];
  float* out = (float*)d_out;

  char* ws = (char*)d_ws;
  const size_t MB = 1024 * 1024;
  __hip_bfloat16* h      = (__hip_bfloat16*)(ws);                 // 16MB [0,16)
  __hip_bfloat16* qk     = (__hip_bfloat16*)(ws + 16*MB);         // 32MB [16,48)
  __hip_bfloat16* vT     = (__hip_bfloat16*)(ws + 48*MB);         // 16MB [48,64)
  __hip_bfloat16* y      = (__hip_bfloat16*)(ws + 64*MB);         // 16MB [64,80)
  float*          x2     = (float*)        (ws + 80*MB);          // 32MB [80,112)
  __hip_bfloat16* h2     = (__hip_bfloat16*)(ws + 64*MB);         // reuse y slot
  __hip_bfloat16* gbuf   = (__hip_bfloat16*)(ws);                 // 64MB reuse [0,64)
  __hip_bfloat16* wattnT = (__hip_bfloat16*)(ws + 112*MB);        // 6MB
  __hip_bfloat16* wprojT = (__hip_bfloat16*)(ws + 118*MB);        // 2MB
  __hip_bfloat16* wfcT   = (__hip_bfloat16*)(ws + 120*MB);        // 8MB
  __hip_bfloat16* wfc2T  = (__hip_bfloat16*)(ws + 128*MB);        // 8MB

  // weights: [K][N] fp32 -> [N][K] bf16
  transpose_bf16<<<dim3(3*C_/32, C_/32), 256, 0, stream>>>(w_attn, wattnT, C_, 3*C_);
  transpose_bf16<<<dim3(C_/32,  C_/32), 256, 0, stream>>>(w_proj, wprojT, C_, C_);
  transpose_bf16<<<dim3(FF_/32, C_/32), 256, 0, stream>>>(w_fc,   wfcT,   C_, FF_);
  transpose_bf16<<<dim3(C_/32, FF_/32), 256, 0, stream>>>(w_fc2,  wfc2T,  FF_, C_);

  // LN1
  ln_bf16<<<NT_, 256, 0, stream>>>(x, ln1_g, ln1_b, h);
  // QKV (Q,K -> qk packed [t][2C]; V -> vT [b*1024+dg][t])
  gemm_bt<0><<<dim3(3*C_/128, NT_/128), 256, 0, stream>>>(h, wattnT, b_attn, nullptr, qk, vT, 3*C_, C_);
  // attention (128-row Q tiles)
  flash_attn<<<dim3(T_/128, B_*NH_), 256, 0, stream>>>(qk, vT, y);
  // proj + residual -> x2 (fp32)
  gemm_bt<1><<<dim3(C_/128, NT_/128), 256, 0, stream>>>(y, wprojT, b_proj, x, x2, nullptr, C_, C_);
  // LN2
  ln_bf16<<<NT_, 256, 0, stream>>>(x2, ln2_g, ln2_b, h2);
  // FC + gelu
  gemm_bt<2><<<dim3(FF_/128, NT_/128), 256, 0, stream>>>(h2, wfcT, b_fc, nullptr, gbuf, nullptr, FF_, C_);
  // FC2 + residual -> out (fp32)
  gemm_bt<3><<<dim3(C_/128, NT_/128), 256, 0, stream>>>(gbuf, wfc2T, b_fc2, x2, out, nullptr, C_, FF_);
}

// Round 5
// 698.527 us; speedup vs baseline: 1.7804x; 1.0593x over previous
//
#include <hip/hip_runtime.h>
#include <hip/hip_bf16.h>

#define B_ 4
#define T_ 2048
#define C_ 1024
#define NH_ 16
#define FF_ 4096
#define NT_ (B_*T_)   // 8192 token rows

typedef short bf16x8 __attribute__((ext_vector_type(8)));
typedef float f32x4 __attribute__((ext_vector_type(4)));

#define LDS_AS(p) ((__attribute__((address_space(3))) uint32_t*)(p))
#define GLB_AS(p) ((const __attribute__((address_space(1))) uint32_t*)(p))

__device__ __forceinline__ float bf2f(__hip_bfloat16 v){ return __bfloat162float(v); }
__device__ __forceinline__ __hip_bfloat16 f2bf(float f){ return __float2bfloat16(f); }

__device__ __forceinline__ f32x4 mfma16(bf16x8 a, bf16x8 b, f32x4 c){
  return __builtin_amdgcn_mfma_f32_16x16x32_bf16(a, b, c, 0, 0, 0);
}

// ---------------- weight transpose + fp32->bf16 cast:  in[K][N] -> out[N][K] ----------------
__global__ __launch_bounds__(256) void transpose_bf16(const float* __restrict__ in,
                                                      __hip_bfloat16* __restrict__ out,
                                                      int K, int N) {
  __shared__ float tile[32][33];
  const int n0 = blockIdx.x * 32, k0 = blockIdx.y * 32;
  const int x = threadIdx.x & 31, y = threadIdx.x >> 5;   // y in 0..7
  #pragma unroll
  for (int i = 0; i < 4; i++)
    tile[y + 8*i][x] = in[(size_t)(k0 + y + 8*i) * N + n0 + x];
  __syncthreads();
  #pragma unroll
  for (int i = 0; i < 4; i++)
    out[(size_t)(n0 + y + 8*i) * K + k0 + x] = f2bf(tile[x][y + 8*i]);
}

// ---------------- LayerNorm fp32 -> bf16 (row = 1024) ----------------
__global__ __launch_bounds__(256) void ln_bf16(const float* __restrict__ x,
                                               const float* __restrict__ g,
                                               const float* __restrict__ b,
                                               __hip_bfloat16* __restrict__ out) {
  const int row = blockIdx.x;
  const int tid = threadIdx.x;
  float4 v = ((const float4*)(x + (size_t)row * C_))[tid];
  float s  = v.x + v.y + v.z + v.w;
  float s2 = v.x*v.x + v.y*v.y + v.z*v.z + v.w*v.w;
  #pragma unroll
  for (int off = 32; off > 0; off >>= 1) {
    s  += __shfl_down(s,  off, 64);
    s2 += __shfl_down(s2, off, 64);
  }
  __shared__ float red[8];
  const int w = tid >> 6, l = tid & 63;
  if (l == 0) { red[w] = s; red[4 + w] = s2; }
  __syncthreads();
  s  = red[0] + red[1] + red[2] + red[3];
  s2 = red[4] + red[5] + red[6] + red[7];
  const float mu   = s * (1.0f / C_);
  const float var  = s2 * (1.0f / C_) - mu * mu;
  const float rstd = rsqrtf(var + 1e-5f);
  float4 gv = ((const float4*)g)[tid];
  float4 bv = ((const float4*)b)[tid];
  ushort4 o;
  __hip_bfloat16 t;
  t = f2bf((v.x - mu) * rstd * gv.x + bv.x); o.x = *(unsigned short*)&t;
  t = f2bf((v.y - mu) * rstd * gv.y + bv.y); o.y = *(unsigned short*)&t;
  t = f2bf((v.z - mu) * rstd * gv.z + bv.z); o.z = *(unsigned short*)&t;
  t = f2bf((v.w - mu) * rstd * gv.w + bv.w); o.w = *(unsigned short*)&t;
  ((ushort4*)out)[(size_t)row * (C_/4) + tid] = o;
}

// ---------------- shared MFMA GEMM:  C[M][N] = A[M][K] * BT[N][K]^T  + epilogue ----------------
// MODE 0: QKV. cols <2048 -> bf16 qk[row][col] (ld 2048); cols >=2048 -> bf16 vT[b,dg,t]
// MODE 1: out f32  = resid + C + bias    (proj)
// MODE 2: out bf16 = gelu(C + bias)      (FC)
// MODE 3: out f32  = resid + C + bias    (FC2)
template <int MODE>
__global__ __launch_bounds__(256) void gemm_bt(const __hip_bfloat16* __restrict__ A,
                                               const __hip_bfloat16* __restrict__ BT,
                                               const float* __restrict__ bias,
                                               const float* __restrict__ resid,
                                               void* __restrict__ outp,
                                               void* __restrict__ outp2,
                                               int N, int K) {
  __shared__ __hip_bfloat16 Als[128 * 32];
  __shared__ __hip_bfloat16 Bls[128 * 32];
  const int tid = threadIdx.x;
  const int w = tid >> 6, l = tid & 63;
  const int tile_n = blockIdx.x * 128;
  const int tile_m = blockIdx.y * 128;
  const int wm = (w >> 1) * 64, wn = (w & 1) * 64;

  f32x4 acc[4][4] = {};

  const int srow = w * 16 + (l >> 2);
  const int scol = (l & 3) * 8;
  const __hip_bfloat16* Ag = A  + (size_t)(tile_m + srow) * K + scol;
  const __hip_bfloat16* Bg = BT + (size_t)(tile_n + srow) * K + scol;
  __hip_bfloat16* AlsW = &Als[(w * 16) * 32];
  __hip_bfloat16* BlsW = &Bls[(w * 16) * 32];

  const int m_ = (l & 15);
  const int kq = (l >> 4) * 8;

  for (int k0 = 0; k0 < K; k0 += 32) {
    __builtin_amdgcn_global_load_lds(GLB_AS(Ag + k0),                 LDS_AS(AlsW),           16, 0, 0);
    __builtin_amdgcn_global_load_lds(GLB_AS(Ag + (size_t)64*K + k0),  LDS_AS(AlsW + 64*32),   16, 0, 0);
    __builtin_amdgcn_global_load_lds(GLB_AS(Bg + k0),                 LDS_AS(BlsW),           16, 0, 0);
    __builtin_amdgcn_global_load_lds(GLB_AS(Bg + (size_t)64*K + k0),  LDS_AS(BlsW + 64*32),   16, 0, 0);
    __syncthreads();
    bf16x8 af[4], bfr[4];
    #pragma unroll
    for (int mi = 0; mi < 4; mi++) af[mi]  = *(const bf16x8*)&Als[(wm + mi*16 + m_) * 32 + kq];
    #pragma unroll
    for (int ni = 0; ni < 4; ni++) bfr[ni] = *(const bf16x8*)&Bls[(wn + ni*16 + m_) * 32 + kq];
    #pragma unroll
    for (int mi = 0; mi < 4; mi++)
      #pragma unroll
      for (int ni = 0; ni < 4; ni++)
        acc[mi][ni] = mfma16(af[mi], bfr[ni], acc[mi][ni]);
    __syncthreads();
  }

  // epilogue: C/D layout col=lane&15, row=(lane>>4)*4+reg
  const int r0 = tile_m + wm + (l >> 4) * 4;
  const int c0 = tile_n + wn + m_;
  #pragma unroll
  for (int mi = 0; mi < 4; mi++) {
    #pragma unroll
    for (int r = 0; r < 4; r++) {
      const int row = r0 + mi * 16 + r;
      #pragma unroll
      for (int ni = 0; ni < 4; ni++) {
        const int col = c0 + ni * 16;
        float v = acc[mi][ni][r] + bias[col];
        if (MODE == 0) {
          if (tile_n < 2 * C_) {
            ((__hip_bfloat16*)outp)[(size_t)row * (2*C_) + col] = f2bf(v);
          } else {
            // vT[(b*1024 + dg)][t], dg = col-2048, b = row>>11, t = row&2047
            const int dg = col - 2 * C_;
            ((__hip_bfloat16*)outp2)[((size_t)((row >> 11) * 1024 + dg)) * T_ + (row & 2047)] = f2bf(v);
          }
        } else if (MODE == 1 || MODE == 3) {
          ((float*)outp)[(size_t)row * N + col] = resid[(size_t)row * N + col] + v;
        } else { // gelu
          const float u = 0.7978845608028654f * (v + 0.044715f * v * v * v);
          const float e = __expf(2.0f * u);
          ((__hip_bfloat16*)outp)[(size_t)row * N + col] = f2bf(v * (1.0f - 1.0f / (e + 1.0f)));
        }
      }
    }
  }
}

// ---------------- flash attention v5 (causal) ----------------
// v4 + (a) XCD-locality swizzle: 1-D grid, xcd = id&7; each XCD runs 8 bh-groups
// x all 16 q-tiles, so the per-bh K/V (512 KB) stays L2-resident on ONE XCD;
// (b) __launch_bounds__(256,2): lift the VGPR cap so all 16 K/V fragment loads
// stay in flight (R4's VGPR_Count=96 serialized them). K loads issued before V
// loads so S-MFMA can start while V is still in flight. No barriers, no K/V LDS,
// fixed-max exp2 softmax, wave-local P LDS round-trip.
// qk: [B*T][2C] bf16 (Q cols 0..1023, K cols 1024..2047); vT: [B*NH*64][T] bf16
__global__ __launch_bounds__(256, 2) void flash_attn(const __hip_bfloat16* __restrict__ qk,
                                                     const __hip_bfloat16* __restrict__ vT,
                                                     __hip_bfloat16* __restrict__ y) {
  const int id  = blockIdx.x;          // 0..1023
  const int xcd = id & 7;
  const int kk  = id >> 3;             // 0..127
  const int bh  = xcd * 8 + (kk >> 4); // 8 bh per XCD
  const int qt  = 15 - (kk & 15);      // longest-first within each XCD
  const int b   = bh >> 4, h = bh & 15;
  const int tid = threadIdx.x, w = tid >> 6, l = tid & 63;
  const int q0 = qt * 128;
  const int m_ = l & 15, q_ = l >> 4;

  __shared__ __hip_bfloat16 Pls[128 * 76];   // wave-local bands, stride 76 (bank-spread)

  // --- Q fragments (A layout): 2 m-frags x 2 k-halves, scaled by 1/8*log2(e) ---
  bf16x8 aq[2][2];
  {
    const float qscale = 0.125f * 1.44269504088896f;
    #pragma unroll
    for (int mf = 0; mf < 2; mf++) {
      const size_t qbase = ((size_t)b * T_ + q0 + w*32 + mf*16 + m_) * (2*C_) + h*64;
      #pragma unroll
      for (int kh = 0; kh < 2; kh++) {
        union { uint4 u; __hip_bfloat16 h8[8]; } t;
        t.u = *(const uint4*)&qk[qbase + kh*32 + q_*8];
        __hip_bfloat16 a[8];
        #pragma unroll
        for (int j = 0; j < 8; j++) a[j] = f2bf(bf2f(t.h8[j]) * qscale);
        aq[mf][kh] = *(const bf16x8*)a;
      }
    }
  }

  f32x4 accO[2][4] = {};
  float lsum[2][4] = {{0.f,0.f,0.f,0.f},{0.f,0.f,0.f,0.f}};

  const size_t kgbase = (size_t)b * T_ * (2*C_) + C_ + h*64;  // + t*(2C) + d
  const size_t vgbase = (size_t)bh * 64 * T_;                 // + d*T + t
  const int ktmax = 2*qt + 1;

  for (int kt = 0; kt <= ktmax; kt++) {
    // --- direct global->register K fragments first (S can start at vmcnt(8)) ---
    bf16x8 bk[4][2], bv[4][2];
    #pragma unroll
    for (int ni = 0; ni < 4; ni++) {
      const __hip_bfloat16* kp = qk + kgbase + (size_t)(kt*64 + ni*16 + m_) * (2*C_);
      union { uint4 u; bf16x8 f; } t0, t1;
      t0.u = *(const uint4*)(kp + q_*8);
      t1.u = *(const uint4*)(kp + 32 + q_*8);
      bk[ni][0] = t0.f; bk[ni][1] = t1.f;
    }
    #pragma unroll
    for (int ni = 0; ni < 4; ni++) {
      const __hip_bfloat16* vp = vT + vgbase + (size_t)(ni*16 + m_) * T_ + kt*64;
      union { uint4 u; bf16x8 f; } t2, t3;
      t2.u = *(const uint4*)(vp + q_*8);
      t3.u = *(const uint4*)(vp + 32 + q_*8);
      bv[ni][0] = t2.f; bv[ni][1] = t3.f;
    }

    // --- S = Q K^T ---
    f32x4 s[2][4];
    #pragma unroll
    for (int ni = 0; ni < 4; ni++)
      #pragma unroll
      for (int mf = 0; mf < 2; mf++) {
        f32x4 z = {};
        z = mfma16(aq[mf][0], bk[ni][0], z);
        s[mf][ni] = mfma16(aq[mf][1], bk[ni][1], z);
      }

    // --- causal mask (only last two k-tiles touch the diagonal) ---
    if (kt >= 2*qt) {
      #pragma unroll
      for (int mf = 0; mf < 2; mf++) {
        const int qrow = q0 + w*32 + mf*16 + q_*4;
        #pragma unroll
        for (int ni = 0; ni < 4; ni++) {
          const int kcol = kt*64 + ni*16 + m_;
          #pragma unroll
          for (int r = 0; r < 4; r++)
            if (kcol > qrow + r) s[mf][ni][r] = -1e30f;
        }
      }
    }

    // --- p = exp2(s); accumulate row-sum per lane; stage P to wave-local LDS ---
    #pragma unroll
    for (int mf = 0; mf < 2; mf++) {
      #pragma unroll
      for (int ni = 0; ni < 4; ni++)
        #pragma unroll
        for (int r = 0; r < 4; r++)
          s[mf][ni][r] = exp2f(s[mf][ni][r]);
      #pragma unroll
      for (int r = 0; r < 4; r++)
        lsum[mf][r] += (s[mf][0][r] + s[mf][1][r]) + (s[mf][2][r] + s[mf][3][r]);
      #pragma unroll
      for (int ni = 0; ni < 4; ni++)
        #pragma unroll
        for (int r = 0; r < 4; r++)
          Pls[(w*32 + mf*16 + q_*4 + r) * 76 + ni*16 + m_] = f2bf(s[mf][ni][r]);
    }

    // --- O += P V (P read back in A layout; wave-local => only lgkmcnt waits) ---
    bf16x8 ap[2][2];
    #pragma unroll
    for (int mf = 0; mf < 2; mf++) {
      ap[mf][0] = *(const bf16x8*)&Pls[(w*32 + mf*16 + m_) * 76 + q_*8];
      ap[mf][1] = *(const bf16x8*)&Pls[(w*32 + mf*16 + m_) * 76 + 32 + q_*8];
    }
    #pragma unroll
    for (int ni = 0; ni < 4; ni++)
      #pragma unroll
      for (int mf = 0; mf < 2; mf++) {
        accO[mf][ni] = mfma16(ap[mf][0], bv[ni][0], accO[mf][ni]);
        accO[mf][ni] = mfma16(ap[mf][1], bv[ni][1], accO[mf][ni]);
      }
  }

  // --- epilogue: reduce Sum(p) across the 16 lanes sharing each row, store O/l ---
  #pragma unroll
  for (int mf = 0; mf < 2; mf++)
    #pragma unroll
    for (int r = 0; r < 4; r++) {
      #pragma unroll
      for (int d = 1; d < 16; d <<= 1)
        lsum[mf][r] += __shfl_xor(lsum[mf][r], d, 64);
    }

  const size_t ybase = ((size_t)b * T_ + q0) * C_ + h*64;
  #pragma unroll
  for (int mf = 0; mf < 2; mf++) {
    #pragma unroll
    for (int r = 0; r < 4; r++) {
      const int row = w*32 + mf*16 + q_*4 + r;
      const float linv = 1.0f / lsum[mf][r];
      #pragma unroll
      for (int ni = 0; ni < 4; ni++)
        y[ybase + (size_t)row * C_ + ni*16 + m_] = f2bf(accO[mf][ni][r] * linv);
    }
  }
}

// ---------------- launch ----------------
extern "C" void kernel_launch(void* const* d_in, const int* in_sizes, int n_in,
                              void* d_out, int out_size, void* d_ws, size_t ws_size,
                              hipStream_t stream) {
  const float* x      = (const float*)d_in[0];
  const float* ln1_g  = (const float*)d_in[1];
  const float* ln1_b  = (const float*)d_in[2];
  const float* w_attn = (const float*)d_in[3];
  const float* b_attn = (const float*)d_in[4];
  const float* w_proj = (const float*)d_in[5];
  const float* b_proj = (const float*)d_in[6];
  const float* ln2_g  = (const float*)d_in[7];
  const float* ln2_b  = (const float*)d_in[8];
  const float* w_fc   = (const float*)d_in[9];
  const float* b_fc   = (const float*)d_in[10];
  const float* w_fc2  = (const float*)d_in[11];
  const float* b_fc2  = (const float*)d_in[12];
  float* out = (float*)d_out;

  char* ws = (char*)d_ws;
  const size_t MB = 1024 * 1024;
  __hip_bfloat16* h      = (__hip_bfloat16*)(ws);                 // 16MB [0,16)
  __hip_bfloat16* qk     = (__hip_bfloat16*)(ws + 16*MB);         // 32MB [16,48)
  __hip_bfloat16* vT     = (__hip_bfloat16*)(ws + 48*MB);         // 16MB [48,64)
  __hip_bfloat16* y      = (__hip_bfloat16*)(ws + 64*MB);         // 16MB [64,80)
  float*          x2     = (float*)        (ws + 80*MB);          // 32MB [80,112)
  __hip_bfloat16* h2     = (__hip_bfloat16*)(ws + 64*MB);         // reuse y slot
  __hip_bfloat16* gbuf   = (__hip_bfloat16*)(ws);                 // 64MB reuse [0,64)
  __hip_bfloat16* wattnT = (__hip_bfloat16*)(ws + 112*MB);        // 6MB
  __hip_bfloat16* wprojT = (__hip_bfloat16*)(ws + 118*MB);        // 2MB
  __hip_bfloat16* wfcT   = (__hip_bfloat16*)(ws + 120*MB);        // 8MB
  __hip_bfloat16* wfc2T  = (__hip_bfloat16*)(ws + 128*MB);        // 8MB

  // weights: [K][N] fp32 -> [N][K] bf16
  transpose_bf16<<<dim3(3*C_/32, C_/32), 256, 0, stream>>>(w_attn, wattnT, C_, 3*C_);
  transpose_bf16<<<dim3(C_/32,  C_/32), 256, 0, stream>>>(w_proj, wprojT, C_, C_);
  transpose_bf16<<<dim3(FF_/32, C_/32), 256, 0, stream>>>(w_fc,   wfcT,   C_, FF_);
  transpose_bf16<<<dim3(C_/32, FF_/32), 256, 0, stream>>>(w_fc2,  wfc2T,  FF_, C_);

  // LN1
  ln_bf16<<<NT_, 256, 0, stream>>>(x, ln1_g, ln1_b, h);
  // QKV (Q,K -> qk packed [t][2C]; V -> vT [b*1024+dg][t])
  gemm_bt<0><<<dim3(3*C_/128, NT_/128), 256, 0, stream>>>(h, wattnT, b_attn, nullptr, qk, vT, 3*C_, C_);
  // attention (128-row Q tiles, XCD-swizzled 1-D grid)
  flash_attn<<<dim3((T_/128) * (B_*NH_)), 256, 0, stream>>>(qk, vT, y);
  // proj + residual -> x2 (fp32)
  gemm_bt<1><<<dim3(C_/128, NT_/128), 256, 0, stream>>>(y, wprojT, b_proj, x, x2, nullptr, C_, C_);
  // LN2
  ln_bf16<<<NT_, 256, 0, stream>>>(x2, ln2_g, ln2_b, h2);
  // FC + gelu
  gemm_bt<2><<<dim3(FF_/128, NT_/128), 256, 0, stream>>>(h2, wfcT, b_fc, nullptr, gbuf, nullptr, FF_, C_);
  // FC2 + residual -> out (fp32)
  gemm_bt<3><<<dim3(C_/128, NT_/128), 256, 0, stream>>>(gbuf, wfc2T, b_fc2, x2, out, nullptr, C_, FF_);
}

// Round 6
// 609.173 us; speedup vs baseline: 2.0416x; 1.1467x over previous
//
#include <hip/hip_runtime.h>
#include <hip/hip_bf16.h>

#define B_ 4
#define T_ 2048
#define C_ 1024
#define NH_ 16
#define FF_ 4096
#define NT_ (B_*T_)   // 8192 token rows

typedef short bf16x8 __attribute__((ext_vector_type(8)));
typedef float f32x4 __attribute__((ext_vector_type(4)));

#define LDS_AS(p) ((__attribute__((address_space(3))) uint32_t*)(p))
#define GLB_AS(p) ((const __attribute__((address_space(1))) uint32_t*)(p))

__device__ __forceinline__ float bf2f(__hip_bfloat16 v){ return __bfloat162float(v); }
__device__ __forceinline__ __hip_bfloat16 f2bf(float f){ return __float2bfloat16(f); }

__device__ __forceinline__ f32x4 mfma16(bf16x8 a, bf16x8 b, f32x4 c){
  return __builtin_amdgcn_mfma_f32_16x16x32_bf16(a, b, c, 0, 0, 0);
}

// ---------------- weight transpose + fp32->bf16 cast:  in[K][N] -> out[N][K] ----------------
__global__ __launch_bounds__(256) void transpose_bf16(const float* __restrict__ in,
                                                      __hip_bfloat16* __restrict__ out,
                                                      int K, int N) {
  __shared__ float tile[32][33];
  const int n0 = blockIdx.x * 32, k0 = blockIdx.y * 32;
  const int x = threadIdx.x & 31, y = threadIdx.x >> 5;   // y in 0..7
  #pragma unroll
  for (int i = 0; i < 4; i++)
    tile[y + 8*i][x] = in[(size_t)(k0 + y + 8*i) * N + n0 + x];
  __syncthreads();
  #pragma unroll
  for (int i = 0; i < 4; i++)
    out[(size_t)(n0 + y + 8*i) * K + k0 + x] = f2bf(tile[x][y + 8*i]);
}

// ---------------- LayerNorm fp32 -> bf16 (row = 1024) ----------------
__global__ __launch_bounds__(256) void ln_bf16(const float* __restrict__ x,
                                               const float* __restrict__ g,
                                               const float* __restrict__ b,
                                               __hip_bfloat16* __restrict__ out) {
  const int row = blockIdx.x;
  const int tid = threadIdx.x;
  float4 v = ((const float4*)(x + (size_t)row * C_))[tid];
  float s  = v.x + v.y + v.z + v.w;
  float s2 = v.x*v.x + v.y*v.y + v.z*v.z + v.w*v.w;
  #pragma unroll
  for (int off = 32; off > 0; off >>= 1) {
    s  += __shfl_down(s,  off, 64);
    s2 += __shfl_down(s2, off, 64);
  }
  __shared__ float red[8];
  const int w = tid >> 6, l = tid & 63;
  if (l == 0) { red[w] = s; red[4 + w] = s2; }
  __syncthreads();
  s  = red[0] + red[1] + red[2] + red[3];
  s2 = red[4] + red[5] + red[6] + red[7];
  const float mu   = s * (1.0f / C_);
  const float var  = s2 * (1.0f / C_) - mu * mu;
  const float rstd = rsqrtf(var + 1e-5f);
  float4 gv = ((const float4*)g)[tid];
  float4 bv = ((const float4*)b)[tid];
  ushort4 o;
  __hip_bfloat16 t;
  t = f2bf((v.x - mu) * rstd * gv.x + bv.x); o.x = *(unsigned short*)&t;
  t = f2bf((v.y - mu) * rstd * gv.y + bv.y); o.y = *(unsigned short*)&t;
  t = f2bf((v.z - mu) * rstd * gv.z + bv.z); o.z = *(unsigned short*)&t;
  t = f2bf((v.w - mu) * rstd * gv.w + bv.w); o.w = *(unsigned short*)&t;
  ((ushort4*)out)[(size_t)row * (C_/4) + tid] = o;
}

// ---------------- shared MFMA GEMM, BK=64, XOR-swizzled staging ----------------
// C[M][N] = A[M][K] * BT[N][K]^T + epilogue
// MODE 0: QKV. cols <2048 -> bf16 qk[row][col] (ld 2048); cols >=2048 -> bf16 vT[b,dg,t]
// MODE 1: out f32  = resid + C + bias    (proj)
// MODE 2: out bf16 = gelu(C + bias)      (FC)
// MODE 3: out f32  = resid + C + bias    (FC2)
// LDS row = 64 elems = 128B = 8 x 16B slots; slot s of row r holds global
// 16B-chunk s^(r&7) (lane fetches chunk (l&7)^(l>>3)), so ds_read_b128 of a
// fragment is 2-way-per-bank (free) without padding.
template <int MODE>
__global__ __launch_bounds__(256) void gemm_bt(const __hip_bfloat16* __restrict__ A,
                                               const __hip_bfloat16* __restrict__ BT,
                                               const float* __restrict__ bias,
                                               const float* __restrict__ resid,
                                               void* __restrict__ outp,
                                               void* __restrict__ outp2,
                                               int N, int K) {
  __shared__ __hip_bfloat16 Als[128 * 64];
  __shared__ __hip_bfloat16 Bls[128 * 64];
  const int tid = threadIdx.x;
  const int w = tid >> 6, l = tid & 63;
  const int tile_n = blockIdx.x * 128;
  const int tile_m = blockIdx.y * 128;
  const int wm = (w >> 1) * 64, wn = (w & 1) * 64;

  f32x4 acc[4][4] = {};

  const int lrow8 = l >> 3;            // 0..7 row within 8-row staging group
  const int gchunk = (l & 7) ^ lrow8;  // which global 16B chunk this lane fetches
  const int m_ = (l & 15);
  const int q_ = (l >> 4);             // 0..3

  for (int k0 = 0; k0 < K; k0 += 64) {
    #pragma unroll
    for (int jj = 0; jj < 2; jj++) {
      const int r0 = w*16 + 8*jj + lrow8;
      __builtin_amdgcn_global_load_lds(GLB_AS(A  + (size_t)(tile_m + r0) * K + k0 + gchunk*8),
                                       LDS_AS(&Als[(w*16 + 8*jj) * 64]), 16, 0, 0);
      __builtin_amdgcn_global_load_lds(GLB_AS(A  + (size_t)(tile_m + 64 + r0) * K + k0 + gchunk*8),
                                       LDS_AS(&Als[(64 + w*16 + 8*jj) * 64]), 16, 0, 0);
      __builtin_amdgcn_global_load_lds(GLB_AS(BT + (size_t)(tile_n + r0) * K + k0 + gchunk*8),
                                       LDS_AS(&Bls[(w*16 + 8*jj) * 64]), 16, 0, 0);
      __builtin_amdgcn_global_load_lds(GLB_AS(BT + (size_t)(tile_n + 64 + r0) * K + k0 + gchunk*8),
                                       LDS_AS(&Bls[(64 + w*16 + 8*jj) * 64]), 16, 0, 0);
    }
    __syncthreads();
    bf16x8 af[2][4], bfr[2][4];
    #pragma unroll
    for (int c = 0; c < 2; c++) {
      #pragma unroll
      for (int mi = 0; mi < 4; mi++) {
        const int row = wm + mi*16 + m_;
        af[c][mi] = *(const bf16x8*)&Als[row * 64 + (((c*4 + q_) ^ (row & 7)) * 8)];
      }
      #pragma unroll
      for (int ni = 0; ni < 4; ni++) {
        const int row = wn + ni*16 + m_;
        bfr[c][ni] = *(const bf16x8*)&Bls[row * 64 + (((c*4 + q_) ^ (row & 7)) * 8)];
      }
    }
    #pragma unroll
    for (int c = 0; c < 2; c++)
      #pragma unroll
      for (int mi = 0; mi < 4; mi++)
        #pragma unroll
        for (int ni = 0; ni < 4; ni++)
          acc[mi][ni] = mfma16(af[c][mi], bfr[c][ni], acc[mi][ni]);
    __syncthreads();
  }

  // epilogue: C/D layout col=lane&15, row=(lane>>4)*4+reg
  const int r0 = tile_m + wm + q_ * 4;
  const int c0 = tile_n + wn + m_;
  #pragma unroll
  for (int mi = 0; mi < 4; mi++) {
    #pragma unroll
    for (int r = 0; r < 4; r++) {
      const int row = r0 + mi * 16 + r;
      #pragma unroll
      for (int ni = 0; ni < 4; ni++) {
        const int col = c0 + ni * 16;
        float v = acc[mi][ni][r] + bias[col];
        if (MODE == 0) {
          if (tile_n < 2 * C_) {
            ((__hip_bfloat16*)outp)[(size_t)row * (2*C_) + col] = f2bf(v);
          } else {
            // vT[(b*1024 + dg)][t], dg = col-2048, b = row>>11, t = row&2047
            const int dg = col - 2 * C_;
            ((__hip_bfloat16*)outp2)[((size_t)((row >> 11) * 1024 + dg)) * T_ + (row & 2047)] = f2bf(v);
          }
        } else if (MODE == 1 || MODE == 3) {
          ((float*)outp)[(size_t)row * N + col] = resid[(size_t)row * N + col] + v;
        } else { // gelu
          const float u = 0.7978845608028654f * (v + 0.044715f * v * v * v);
          const float e = __expf(2.0f * u);
          ((__hip_bfloat16*)outp)[(size_t)row * N + col] = f2bf(v * (1.0f - 1.0f / (e + 1.0f)));
        }
      }
    }
  }
}

// ---------------- flash attention v6 (causal) ----------------
// Persistent balanced blocks: grid 512, each block runs TWO (bh,qt) units with
// qt = p and 15-p  =>  every block does exactly 36 k-iterations (no tail).
// XCD swizzle keeps each bh's K/V on one XCD's L2. K/V register DOUBLE-BUFFER
// written explicitly (two reg sets, kt-loop unrolled x2 - iteration count per
// unit is always even), so next tile's 16 loads fly while current tile computes.
// No barriers, fixed-max exp2 softmax, wave-local P LDS round-trip.
// qk: [B*T][2C] bf16 (Q cols 0..1023, K cols 1024..2047); vT: [B*NH*64][T] bf16
__global__ __launch_bounds__(256, 2) void flash_attn(const __hip_bfloat16* __restrict__ qk,
                                                     const __hip_bfloat16* __restrict__ vT,
                                                     __hip_bfloat16* __restrict__ y) {
  const int id  = blockIdx.x;          // 0..511
  const int xcd = id & 7;
  const int jj  = id >> 3;             // 0..63
  const int bh  = xcd * 8 + (jj >> 3); // 8 bh per XCD
  const int p   = jj & 7;              // pair index: units qt=p and qt=15-p
  const int b   = bh >> 4, h = bh & 15;
  const int tid = threadIdx.x, w = tid >> 6, l = tid & 63;
  const int m_ = l & 15, q_ = l >> 4;

  __shared__ __hip_bfloat16 Pls[128 * 76];   // wave-local bands, stride 76

  const size_t kgbase = (size_t)b * T_ * (2*C_) + C_ + h*64;  // + t*(2C) + d
  const size_t vgbase = (size_t)bh * 64 * T_;                 // + d*T + t

#define LOAD_KV(bkX, bvX, kt_) do {                                                   \
    _Pragma("unroll")                                                                 \
    for (int ni = 0; ni < 4; ni++) {                                                  \
      const __hip_bfloat16* kp = qk + kgbase + (size_t)((kt_)*64 + ni*16 + m_)*(2*C_);\
      union { uint4 u; bf16x8 f; } t0, t1;                                            \
      t0.u = *(const uint4*)(kp + q_*8);                                              \
      t1.u = *(const uint4*)(kp + 32 + q_*8);                                         \
      bkX[ni][0] = t0.f; bkX[ni][1] = t1.f;                                           \
    }                                                                                 \
    _Pragma("unroll")                                                                 \
    for (int ni = 0; ni < 4; ni++) {                                                  \
      const __hip_bfloat16* vp = vT + vgbase + (size_t)(ni*16 + m_)*T_ + (kt_)*64;    \
      union { uint4 u; bf16x8 f; } t2, t3;                                            \
      t2.u = *(const uint4*)(vp + q_*8);                                              \
      t3.u = *(const uint4*)(vp + 32 + q_*8);                                         \
      bvX[ni][0] = t2.f; bvX[ni][1] = t3.f;                                           \
    }                                                                                 \
  } while (0)

#define COMPUTE(bkX, bvX, kt_) do {                                                   \
    f32x4 s[2][4];                                                                    \
    _Pragma("unroll")                                                                 \
    for (int ni = 0; ni < 4; ni++)                                                    \
      _Pragma("unroll")                                                               \
      for (int mf = 0; mf < 2; mf++) {                                                \
        f32x4 z = {};                                                                 \
        z = mfma16(aq[mf][0], bkX[ni][0], z);                                         \
        s[mf][ni] = mfma16(aq[mf][1], bkX[ni][1], z);                                 \
      }                                                                               \
    if ((kt_) >= 2*qt) {                                                              \
      _Pragma("unroll")                                                               \
      for (int mf = 0; mf < 2; mf++) {                                                \
        const int qrow = q0 + w*32 + mf*16 + q_*4;                                    \
        _Pragma("unroll")                                                             \
        for (int ni = 0; ni < 4; ni++) {                                              \
          const int kcol = (kt_)*64 + ni*16 + m_;                                     \
          _Pragma("unroll")                                                           \
          for (int r = 0; r < 4; r++)                                                 \
            if (kcol > qrow + r) s[mf][ni][r] = -1e30f;                               \
        }                                                                             \
      }                                                                               \
    }                                                                                 \
    _Pragma("unroll")                                                                 \
    for (int mf = 0; mf < 2; mf++) {                                                  \
      _Pragma("unroll")                                                               \
      for (int ni = 0; ni < 4; ni++)                                                  \
        _Pragma("unroll")                                                             \
        for (int r = 0; r < 4; r++)                                                   \
          s[mf][ni][r] = exp2f(s[mf][ni][r]);                                         \
      _Pragma("unroll")                                                               \
      for (int r = 0; r < 4; r++)                                                     \
        lsum[mf][r] += (s[mf][0][r] + s[mf][1][r]) + (s[mf][2][r] + s[mf][3][r]);     \
      _Pragma("unroll")                                                               \
      for (int ni = 0; ni < 4; ni++)                                                  \
        _Pragma("unroll")                                                             \
        for (int r = 0; r < 4; r++)                                                   \
          Pls[(w*32 + mf*16 + q_*4 + r) * 76 + ni*16 + m_] = f2bf(s[mf][ni][r]);      \
    }                                                                                 \
    bf16x8 ap[2][2];                                                                  \
    _Pragma("unroll")                                                                 \
    for (int mf = 0; mf < 2; mf++) {                                                  \
      ap[mf][0] = *(const bf16x8*)&Pls[(w*32 + mf*16 + m_) * 76 + q_*8];              \
      ap[mf][1] = *(const bf16x8*)&Pls[(w*32 + mf*16 + m_) * 76 + 32 + q_*8];         \
    }                                                                                 \
    _Pragma("unroll")                                                                 \
    for (int ni = 0; ni < 4; ni++)                                                    \
      _Pragma("unroll")                                                               \
      for (int mf = 0; mf < 2; mf++) {                                                \
        accO[mf][ni] = mfma16(ap[mf][0], bvX[ni][0], accO[mf][ni]);                   \
        accO[mf][ni] = mfma16(ap[mf][1], bvX[ni][1], accO[mf][ni]);                   \
      }                                                                               \
  } while (0)

  #pragma unroll 1
  for (int ui = 0; ui < 2; ui++) {
    const int qt = ui ? (15 - p) : p;
    const int q0 = qt * 128;

    // --- Q fragments (A layout): 2 m-frags x 2 k-halves, scaled by 1/8*log2(e) ---
    bf16x8 aq[2][2];
    {
      const float qscale = 0.125f * 1.44269504088896f;
      #pragma unroll
      for (int mf = 0; mf < 2; mf++) {
        const size_t qbase = ((size_t)b * T_ + q0 + w*32 + mf*16 + m_) * (2*C_) + h*64;
        #pragma unroll
        for (int kh = 0; kh < 2; kh++) {
          union { uint4 u; __hip_bfloat16 h8[8]; } t;
          t.u = *(const uint4*)&qk[qbase + kh*32 + q_*8];
          __hip_bfloat16 a[8];
          #pragma unroll
          for (int jx = 0; jx < 8; jx++) a[jx] = f2bf(bf2f(t.h8[jx]) * qscale);
          aq[mf][kh] = *(const bf16x8*)a;
        }
      }
    }

    f32x4 accO[2][4] = {};
    float lsum[2][4] = {{0.f,0.f,0.f,0.f},{0.f,0.f,0.f,0.f}};
    const int ktmax = 2*qt + 1;   // iteration count 2qt+2: always even

    bf16x8 bkA[4][2], bvA[4][2], bkB[4][2], bvB[4][2];
    LOAD_KV(bkA, bvA, 0);
    for (int kt = 0; kt <= ktmax; kt += 2) {
      LOAD_KV(bkB, bvB, kt + 1);
      COMPUTE(bkA, bvA, kt);
      if (kt + 2 <= ktmax) LOAD_KV(bkA, bvA, kt + 2);
      COMPUTE(bkB, bvB, kt + 1);
    }

    // --- epilogue: reduce Sum(p) across the 16 lanes sharing each row, store O/l ---
    #pragma unroll
    for (int mf = 0; mf < 2; mf++)
      #pragma unroll
      for (int r = 0; r < 4; r++) {
        #pragma unroll
        for (int d = 1; d < 16; d <<= 1)
          lsum[mf][r] += __shfl_xor(lsum[mf][r], d, 64);
      }

    const size_t ybase = ((size_t)b * T_ + q0) * C_ + h*64;
    #pragma unroll
    for (int mf = 0; mf < 2; mf++) {
      #pragma unroll
      for (int r = 0; r < 4; r++) {
        const int row = w*32 + mf*16 + q_*4 + r;
        const float linv = 1.0f / lsum[mf][r];
        #pragma unroll
        for (int ni = 0; ni < 4; ni++)
          y[ybase + (size_t)row * C_ + ni*16 + m_] = f2bf(accO[mf][ni][r] * linv);
      }
    }
  }
#undef LOAD_KV
#undef COMPUTE
}

// ---------------- launch ----------------
extern "C" void kernel_launch(void* const* d_in, const int* in_sizes, int n_in,
                              void* d_out, int out_size, void* d_ws, size_t ws_size,
                              hipStream_t stream) {
  const float* x      = (const float*)d_in[0];
  const float* ln1_g  = (const float*)d_in[1];
  const float* ln1_b  = (const float*)d_in[2];
  const float* w_attn = (const float*)d_in[3];
  const float* b_attn = (const float*)d_in[4];
  const float* w_proj = (const float*)d_in[5];
  const float* b_proj = (const float*)d_in[6];
  const float* ln2_g  = (const float*)d_in[7];
  const float* ln2_b  = (const float*)d_in[8];
  const float* w_fc   = (const float*)d_in[9];
  const float* b_fc   = (const float*)d_in[10];
  const float* w_fc2  = (const float*)d_in[11];
  const float* b_fc2  = (const float*)d_in[12];
  float* out = (float*)d_out;

  char* ws = (char*)d_ws;
  const size_t MB = 1024 * 1024;
  __hip_bfloat16* h      = (__hip_bfloat16*)(ws);                 // 16MB [0,16)
  __hip_bfloat16* qk     = (__hip_bfloat16*)(ws + 16*MB);         // 32MB [16,48)
  __hip_bfloat16* vT     = (__hip_bfloat16*)(ws + 48*MB);         // 16MB [48,64)
  __hip_bfloat16* y      = (__hip_bfloat16*)(ws + 64*MB);         // 16MB [64,80)
  float*          x2     = (float*)        (ws + 80*MB);          // 32MB [80,112)
  __hip_bfloat16* h2     = (__hip_bfloat16*)(ws + 64*MB);         // reuse y slot
  __hip_bfloat16* gbuf   = (__hip_bfloat16*)(ws);                 // 64MB reuse [0,64)
  __hip_bfloat16* wattnT = (__hip_bfloat16*)(ws + 112*MB);        // 6MB
  __hip_bfloat16* wprojT = (__hip_bfloat16*)(ws + 118*MB);        // 2MB
  __hip_bfloat16* wfcT   = (__hip_bfloat16*)(ws + 120*MB);        // 8MB
  __hip_bfloat16* wfc2T  = (__hip_bfloat16*)(ws + 128*MB);        // 8MB

  // weights: [K][N] fp32 -> [N][K] bf16
  transpose_bf16<<<dim3(3*C_/32, C_/32), 256, 0, stream>>>(w_attn, wattnT, C_, 3*C_);
  transpose_bf16<<<dim3(C_/32,  C_/32), 256, 0, stream>>>(w_proj, wprojT, C_, C_);
  transpose_bf16<<<dim3(FF_/32, C_/32), 256, 0, stream>>>(w_fc,   wfcT,   C_, FF_);
  transpose_bf16<<<dim3(C_/32, FF_/32), 256, 0, stream>>>(w_fc2,  wfc2T,  FF_, C_);

  // LN1
  ln_bf16<<<NT_, 256, 0, stream>>>(x, ln1_g, ln1_b, h);
  // QKV (Q,K -> qk packed [t][2C]; V -> vT [b*1024+dg][t])
  gemm_bt<0><<<dim3(3*C_/128, NT_/128), 256, 0, stream>>>(h, wattnT, b_attn, nullptr, qk, vT, 3*C_, C_);
  // attention (persistent balanced blocks)
  flash_attn<<<dim3(512), 256, 0, stream>>>(qk, vT, y);
  // proj + residual -> x2 (fp32)
  gemm_bt<1><<<dim3(C_/128, NT_/128), 256, 0, stream>>>(y, wprojT, b_proj, x, x2, nullptr, C_, C_);
  // LN2
  ln_bf16<<<NT_, 256, 0, stream>>>(x2, ln2_g, ln2_b, h2);
  // FC + gelu
  gemm_bt<2><<<dim3(FF_/128, NT_/128), 256, 0, stream>>>(h2, wfcT, b_fc, nullptr, gbuf, nullptr, FF_, C_);
  // FC2 + residual -> out (fp32)
  gemm_bt<3><<<dim3(C_/128, NT_/128), 256, 0, stream>>>(gbuf, wfc2T, b_fc2, x2, out, nullptr, C_, FF_);
}